// Round 10
// baseline (1816.661 us; speedup 1.0000x reference)
//
#include <hip/hip_runtime.h>
#include <hip/hip_bf16.h>

#define B_ 128
#define S_ 512
#define C_ 16
#define E_ 100
#define CE_ 30
#define NF_ 25
#define H_ 128
#define T_ 17
#define LSTM_IN_ 175
#define KP_ 192        // feats K padded to multiple of 32 for MFMA
#define G4_ 512        // 4*H

typedef __hip_bfloat16 bf16;
typedef short bf16x8 __attribute__((ext_vector_type(8)));
typedef float f32x4 __attribute__((ext_vector_type(4)));

// ---------- helpers ----------
__device__ __forceinline__ float bf2f(unsigned short u){
  union { unsigned int i; float f; } v; v.i = ((unsigned int)u) << 16; return v.f;
}
__device__ __forceinline__ float sigm_f(float x){
  float e = __expf(-x);
  return __builtin_amdgcn_rcpf(1.0f + e);
}
__device__ __forceinline__ float tanh_f(float x){
  x = fminf(15.0f, fmaxf(-15.0f, x));
  float e = __expf(-2.0f*x);
  return (1.0f - e) * __builtin_amdgcn_rcpf(1.0f + e);
}
__device__ __forceinline__ short bf16bits(float f){
  bf16 b = __float2bfloat16(f);
  return *(short*)&b;
}

// ---------- K-1: zero the K-pad columns of feats ----------
__global__ __launch_bounds__(256) void zero_pad_kernel(bf16* __restrict__ feats){
  int task = blockIdx.x*256 + threadIdx.x;      // 65536*17 = 1,114,112 exact
  int word = task / 17;
  int col = LSTM_IN_ + (task - word*17);        // 175..191
  feats[(size_t)word*KP_ + col] = __float2bfloat16(0.0f);
}

// ---------- K0: word embedding gather -> feats[:, 0:100] ----------
__global__ __launch_bounds__(256) void word_emb_kernel(const int* __restrict__ x,
    const float* __restrict__ wemb, bf16* __restrict__ feats){
  int word = blockIdx.x*2 + (threadIdx.x>>7);
  int e = threadIdx.x & 127;
  if (e < E_) feats[(size_t)word*KP_ + e] = __float2bfloat16(wemb[(size_t)x[word]*E_ + e]);
}

// ---------- K1: char conv (f32, stride-192 out) ----------
template<int KW>
__global__ __launch_bounds__(256) void char_conv_kernel(const int* __restrict__ char_x,
    const float* __restrict__ cemb, const float* __restrict__ W,
    const float* __restrict__ bias, bf16* __restrict__ feats, int out_off){
  int task = blockIdx.x*256 + threadIdx.x;     // 65536*25 tasks
  int word = task / NF_;
  int fi = task - word*NF_;
  const int* cx = char_x + word*C_;
  float w[KW*CE_];
  #pragma unroll
  for (int i=0;i<KW*CE_;++i) w[i] = W[fi*CE_*KW + i];   // [fi][e][dx]
  const int NP = C_ - KW + 1;
  float acc[C_ - KW + 1];
  #pragma unroll
  for (int p=0;p<NP;++p) acc[p] = 0.0f;
  #pragma unroll
  for (int c=0;c<C_;++c){
    int ci = cx[c];
    const float* ce = cemb + ci*CE_;
    #pragma unroll
    for (int e=0;e<CE_;++e){
      float v = ce[e];
      #pragma unroll
      for (int dx=0;dx<KW;++dx){
        int p = c - dx;
        if (p >= 0 && p < NP) acc[p] = fmaf(v, w[e*KW+dx], acc[p]);
      }
    }
  }
  float m = acc[0];
  #pragma unroll
  for (int p=1;p<NP;++p) m = fmaxf(m, acc[p]);
  feats[(size_t)word*KP_ + out_off + fi] = __float2bfloat16(fmaxf(0.0f, m + bias[fi]));
}

// ---------- W_ih f32 [512][175] (x2 dirs) -> bf16 [1024][192] zero-padded ----------
__global__ __launch_bounds__(192) void wpack_kernel(const float* __restrict__ Wf,
    const float* __restrict__ Wb, bf16* __restrict__ wpk){
  int g = blockIdx.x;            // 0..1023
  int k = threadIdx.x;           // 0..191
  float v = 0.0f;
  if (k < LSTM_IN_) v = (g < 512) ? Wf[g*LSTM_IN_ + k] : Wb[(g-512)*LSTM_IN_ + k];
  wpk[(size_t)g*KP_ + k] = __float2bfloat16(v);
}

// ---------- Whh f32 [512][128] (x2 dirs) -> bf16 [2][512][128] ----------
__global__ __launch_bounds__(256) void whh_pack_kernel(const float* __restrict__ Wf,
    const float* __restrict__ Wb, bf16* __restrict__ wpk2){
  int idx = blockIdx.x*256 + threadIdx.x;   // 131072 exact (512 blocks)
  int dir = idx >> 16;
  int rem = idx & 65535;
  const float* W = dir ? Wb : Wf;
  wpk2[idx] = __float2bfloat16(W[rem]);
}

// ---------- h2t_W f32 [17][256] -> bf16 wem[2][32][128] (tags 17..31 = 0) ----------
__global__ __launch_bounds__(256) void wem_pack_kernel(const float* __restrict__ h2tW,
    bf16* __restrict__ wem){
  int idx = blockIdx.x*256 + threadIdx.x;   // 8192 exact (32 blocks)
  int d = idx >> 12;
  int rem = idx & 4095;
  int t = rem >> 7, k = rem & 127;
  float v = (t < T_) ? h2tW[t*(2*H_) + d*H_ + k] : 0.0f;
  wem[idx] = __float2bfloat16(v);
}

// ---------- K2: pre = feats @ W_ih^T + b  (MFMA bf16, global_load_lds, dbuf) ----------
__global__ __launch_bounds__(256, 3) void pre_gemm_mfma(const bf16* __restrict__ feats,
    const bf16* __restrict__ wpk, const float* __restrict__ bf_,
    const float* __restrict__ bb_, bf16* __restrict__ pre){
  __shared__ __align__(16) short lds[16384];   // 32KB: 2 x (A 4096 + B 4096); reused as C-stage
  int br = blockIdx.x;           // 0..511
  int bc = blockIdx.y;           // 0..7
  int dir = bc >> 2;
  int g0 = (bc & 3) * 128;
  const float* bias = dir ? bb_ : bf_;
  int tid = threadIdx.x;
  int wave = tid >> 6, lane = tid & 63;
  int wr = wave >> 1, wc = wave & 1;
  int lrow = lane & 15, lkb = lane >> 4;
  const bf16* Arow = feats + (size_t)br*128*KP_;
  const bf16* Brow = wpk + (size_t)(dir*512 + g0)*KP_;

  auto stage = [&](int bufbase, int k0){
    int s0 = wave*2, s1 = s0 + 1;
    __builtin_amdgcn_global_load_lds(
        (const __attribute__((address_space(1))) void*)(Arow + (size_t)(s0*16 + lrow)*KP_ + k0 + lkb*8),
        (__attribute__((address_space(3))) void*)&lds[bufbase + s0*512], 16, 0, 0);
    __builtin_amdgcn_global_load_lds(
        (const __attribute__((address_space(1))) void*)(Arow + (size_t)(s1*16 + lrow)*KP_ + k0 + lkb*8),
        (__attribute__((address_space(3))) void*)&lds[bufbase + s1*512], 16, 0, 0);
    __builtin_amdgcn_global_load_lds(
        (const __attribute__((address_space(1))) void*)(Brow + (size_t)(s0*16 + lrow)*KP_ + k0 + lkb*8),
        (__attribute__((address_space(3))) void*)&lds[bufbase + 4096 + s0*512], 16, 0, 0);
    __builtin_amdgcn_global_load_lds(
        (const __attribute__((address_space(1))) void*)(Brow + (size_t)(s1*16 + lrow)*KP_ + k0 + lkb*8),
        (__attribute__((address_space(3))) void*)&lds[bufbase + 4096 + s1*512], 16, 0, 0);
  };

  f32x4 acc[4][4];
  #pragma unroll
  for (int i=0;i<4;++i)
    #pragma unroll
    for (int j=0;j<4;++j) acc[i][j] = (f32x4){0.f,0.f,0.f,0.f};

  stage(0, 0);
  __syncthreads();
  int cur = 0;
  for (int t = 0; t < 6; ++t){
    if (t < 5) stage((cur^1)*8192, (t+1)*32);
    const short* A  = &lds[cur*8192];
    const short* Bv = &lds[cur*8192 + 4096];
    bf16x8 af[4], bfr[4];
    #pragma unroll
    for (int i=0;i<4;++i) af[i]  = *(const bf16x8*)&A[(wr*4+i)*512 + lane*8];
    #pragma unroll
    for (int j=0;j<4;++j) bfr[j] = *(const bf16x8*)&Bv[(wc*4+j)*512 + lane*8];
    #pragma unroll
    for (int i=0;i<4;++i)
      #pragma unroll
      for (int j=0;j<4;++j)
        acc[i][j] = __builtin_amdgcn_mfma_f32_16x16x32_bf16(af[i], bfr[j], acc[i][j], 0, 0, 0);
    __syncthreads();
    cur ^= 1;
  }

  // epilogue: swizzled C-stage in LDS, then coalesced 16B global stores
  int col_l = lane & 15;
  int row_l = (lane >> 4) * 4;
  float bias_v[4];
  #pragma unroll
  for (int j=0;j<4;++j) bias_v[j] = bias[g0 + wc*64 + j*16 + col_l];
  #pragma unroll
  for (int i=0;i<4;++i){
    #pragma unroll
    for (int q=0;q<4;++q){
      int r = wr*64 + i*16 + row_l + q;
      #pragma unroll
      for (int j=0;j<4;++j){
        int cbyte = (wc*64 + j*16 + col_l) * 2;
        int addr = r*256 + (cbyte ^ ((r & 7) << 4));
        *(short*)((char*)lds + addr) = bf16bits(acc[i][j][q] + bias_v[j]);
      }
    }
  }
  __syncthreads();
  int r = tid >> 1, half = tid & 1;
  int word = br*128 + r;
  int bidx = word >> 9, sidx = word & 511;
  bf16* dst = pre + ((size_t)(dir*B_ + bidx)*S_ + sidx)*G4_ + g0 + half*64;
  #pragma unroll
  for (int k=0;k<8;++k){
    int boff = (half*128 + k*16) ^ ((r & 7) << 4);
    int4 v = *(const int4*)((const char*)lds + r*256 + boff);
    *(int4*)((char*)dst + k*16) = v;
  }
}

// ---------- K3: LSTM + fused emissions; Whh/Wem pinned in VGPRs ----------
// block = (dir, batch-group of 16). 16 blocks x 512 threads (8 waves).
__global__ __launch_bounds__(512) void lstm_mfma_kernel(
    const bf16* __restrict__ pre, const bf16* __restrict__ wpk2,
    const bf16* __restrict__ wem, const float* __restrict__ h2tb,
    float* __restrict__ em_f, float* __restrict__ em_b){
  int blk = blockIdx.x;           // 0..15
  int dir = blk & 1;
  int bg  = blk >> 1;             // 0..7
  int tid = threadIdx.x;
  int w = tid >> 6, l = tid & 63;
  int lm = l & 15, lk = l >> 4;
  int gcol = 16*w + lm;

  // recurrence B-frags (64 VGPRs) — pinned against rematerialization
  bf16x8 Bf[4][4];
  {
    const bf16* Wd = wpk2 + (size_t)dir*512*128;
    #pragma unroll
    for (int ct=0; ct<4; ++ct)
      #pragma unroll
      for (int kk=0; kk<4; ++kk){
        Bf[ct][kk] = *(const bf16x8*)(Wd + (ct*128 + gcol)*128 + 32*kk + lk*8);
        asm volatile("" : "+v"(Bf[ct][kk]));
      }
  }
  // emission B-frags (waves 0-1; tag = w*16+lm, wave1 rows 16..31 are zero-padded)
  int tag = w*16 + lm;
  bf16x8 Ef[4];
  {
    int trow = (w < 2) ? tag : 0;
    #pragma unroll
    for (int kk=0; kk<4; ++kk){
      Ef[kk] = *(const bf16x8*)(wem + ((size_t)dir*32 + trow)*128 + 32*kk + lk*8);
      asm volatile("" : "+v"(Ef[kk]));
    }
  }
  float embias = 0.0f;
  if (dir == 0 && w < 2 && tag < T_) embias = h2tb[tag];

  __shared__ __align__(16) short h_sh[2][2048];
  for (int i = tid; i < 1024; i += 512) ((int*)h_sh[0])[i] = 0;

  float c[4] = {0.f, 0.f, 0.f, 0.f};
  const bf16* preB = pre + (size_t)(dir*B_ + bg*16) * (S_*G4_);
  int sd  = dir ? -1 : 1;
  int sdG = sd * G4_;
  int sdT = sd * T_;
  int idx0 = dir ? (S_-1) : 0;

  const bf16 *p0 = preB + ((size_t)(lk*4+0)*S_ + idx0)*G4_ + gcol;
  const bf16 *p1 = preB + ((size_t)(lk*4+1)*S_ + idx0)*G4_ + gcol;
  const bf16 *p2 = preB + ((size_t)(lk*4+2)*S_ + idx0)*G4_ + gcol;
  const bf16 *p3 = preB + ((size_t)(lk*4+3)*S_ + idx0)*G4_ + gcol;

  float* emBase = (dir ? em_b : em_f) + (size_t)(bg*16)*S_*T_;
  float *e0 = emBase + ((size_t)(lk*4+0)*S_ + idx0)*T_ + tag;
  float *e1 = emBase + ((size_t)(lk*4+1)*S_ + idx0)*T_ + tag;
  float *e2 = emBase + ((size_t)(lk*4+2)*S_ + idx0)*T_ + tag;
  float *e3 = emBase + ((size_t)(lk*4+3)*S_ + idx0)*T_ + tag;

  unsigned short pfA[16], pfB[16];
  auto LOADPF = [&](unsigned short (&pf)[16], bool g){
    if (g){
      pf[0]  = *(const unsigned short*)(p0);     pf[1]  = *(const unsigned short*)(p0+128);
      pf[2]  = *(const unsigned short*)(p0+256); pf[3]  = *(const unsigned short*)(p0+384);
      pf[4]  = *(const unsigned short*)(p1);     pf[5]  = *(const unsigned short*)(p1+128);
      pf[6]  = *(const unsigned short*)(p1+256); pf[7]  = *(const unsigned short*)(p1+384);
      pf[8]  = *(const unsigned short*)(p2);     pf[9]  = *(const unsigned short*)(p2+128);
      pf[10] = *(const unsigned short*)(p2+256); pf[11] = *(const unsigned short*)(p2+384);
      pf[12] = *(const unsigned short*)(p3);     pf[13] = *(const unsigned short*)(p3+128);
      pf[14] = *(const unsigned short*)(p3+256); pf[15] = *(const unsigned short*)(p3+384);
    }
    p0 += sdG; p1 += sdG; p2 += sdG; p3 += sdG;
  };

  auto STEP = [&](unsigned short (&pfuse)[16], int s, const short* src, short* dst){
    f32x4 a0, a1, a2, a3;
    #pragma unroll
    for (int q=0;q<4;++q){
      a0[q] = bf2f(pfuse[q*4+0]);
      a1[q] = bf2f(pfuse[q*4+1]);
      a2[q] = bf2f(pfuse[q*4+2]);
      a3[q] = bf2f(pfuse[q*4+3]);
    }
    LOADPF(pfuse, s+2 < S_);
    bf16x8 af[4];
    #pragma unroll
    for (int kk=0;kk<4;++kk){
      int sc = ((4*kk + lk) ^ lm) & 15;
      af[kk] = *(const bf16x8*)((const char*)src + lm*256 + sc*16);
      a0 = __builtin_amdgcn_mfma_f32_16x16x32_bf16(af[kk], Bf[0][kk], a0, 0, 0, 0);
      a1 = __builtin_amdgcn_mfma_f32_16x16x32_bf16(af[kk], Bf[1][kk], a1, 0, 0, 0);
      a2 = __builtin_amdgcn_mfma_f32_16x16x32_bf16(af[kk], Bf[2][kk], a2, 0, 0, 0);
      a3 = __builtin_amdgcn_mfma_f32_16x16x32_bf16(af[kk], Bf[3][kk], a3, 0, 0, 0);
    }
    // fused emissions for step s-1 (af IS h[s-1])
    if (w < 2 && s > 0){
      f32x4 emq;
      emq[0]=embias; emq[1]=embias; emq[2]=embias; emq[3]=embias;
      #pragma unroll
      for (int kk=0;kk<4;++kk)
        emq = __builtin_amdgcn_mfma_f32_16x16x32_bf16(af[kk], Ef[kk], emq, 0, 0, 0);
      if (tag < T_){ *e0 = emq[0]; *e1 = emq[1]; *e2 = emq[2]; *e3 = emq[3]; }
    }
    if (s > 0){ e0 += sdT; e1 += sdT; e2 += sdT; e3 += sdT; }
    float hv[4];
    #pragma unroll
    for (int q=0;q<4;++q){
      float iv = sigm_f(a0[q]);
      float fv = sigm_f(a1[q]);
      float gv = tanh_f(a2[q]);
      float ov = sigm_f(a3[q]);
      c[q] = fmaf(fv, c[q], iv*gv);
      hv[q] = ov * tanh_f(c[q]);
    }
    #pragma unroll
    for (int q=0;q<4;++q){
      int b = lk*4 + q;
      int scw = ((gcol >> 3) ^ b) & 15;
      *(short*)((char*)dst + b*256 + scw*16 + (gcol & 7)*2) = bf16bits(hv[q]);
    }
    asm volatile("s_waitcnt lgkmcnt(0)" ::: "memory");
    __builtin_amdgcn_s_barrier();
    asm volatile("" ::: "memory");
  };

  __syncthreads();                // h_sh[0] zero-init visible
  LOADPF(pfA, true);
  LOADPF(pfB, true);
  for (int s = 0; s < S_; s += 2){
    STEP(pfA, s,   h_sh[0], h_sh[1]);
    STEP(pfB, s+1, h_sh[1], h_sh[0]);
  }
  // emissions for the last step (h[S-1] sits in h_sh[0])
  if (w < 2){
    f32x4 emq;
    emq[0]=embias; emq[1]=embias; emq[2]=embias; emq[3]=embias;
    #pragma unroll
    for (int kk=0;kk<4;++kk){
      int sc = ((4*kk + lk) ^ lm) & 15;
      bf16x8 af = *(const bf16x8*)((const char*)h_sh[0] + lm*256 + sc*16);
      emq = __builtin_amdgcn_mfma_f32_16x16x32_bf16(af, Ef[kk], emq, 0, 0, 0);
    }
    if (tag < T_){ *e0 = emq[0]; *e1 = emq[1]; *e2 = emq[2]; *e3 = emq[3]; }
  }
}

// ---------- K5a: gold-path score (em split into two dirs) ----------
__global__ __launch_bounds__(256) void score_kernel(const int* __restrict__ tags,
    const float* __restrict__ em_f, const float* __restrict__ em_b,
    const float* __restrict__ start,
    const float* __restrict__ end_, const float* __restrict__ trans,
    float* __restrict__ score){
  int b = blockIdx.x;
  int tid = threadIdx.x;
  const int* tg = tags + b*S_;
  const float* ef = em_f + (size_t)b*S_*T_;
  const float* eb = em_b + (size_t)b*S_*T_;
  float s = 0.0f;
  for (int t = tid; t < S_; t += 256){
    int cur = tg[t];
    s += ef[(size_t)t*T_ + cur] + eb[(size_t)t*T_ + cur];
    if (t > 0) s += trans[tg[t-1]*T_ + cur];
  }
  if (tid == 0) s += start[tg[0]] + end_[tg[S_-1]];
  __shared__ float red[256];
  red[tid] = s; __syncthreads();
  for (int off=128; off; off>>=1){
    if (tid < off) red[tid] += red[tid+off];
    __syncthreads();
  }
  if (tid == 0) score[b] = red[0];
}

// ---------- K5b: CRF forward recursion — 2 batches per wave, tree reductions ----------
__global__ __launch_bounds__(64) void crf_alpha_kernel(const float* __restrict__ em_f,
    const float* __restrict__ em_b,
    const float* __restrict__ start, const float* __restrict__ end_,
    const float* __restrict__ trans, float* __restrict__ logZ){
  int pair = blockIdx.x;            // 0..63
  int lane = threadIdx.x;           // one wave
  int half = lane >> 5;
  int j = lane & 31;
  int b = pair*2 + half;
  bool act = j < T_;
  const float* ef = em_f + (size_t)b*S_*T_;
  const float* eb = em_b + (size_t)b*S_*T_;
  __shared__ float al2[2][32];
  float tcol[T_];
  if (act){
    #pragma unroll
    for (int i=0;i<T_;++i) tcol[i] = trans[i*T_ + j];
    al2[half][j] = start[j] + ef[j] + eb[j];
  }
  float ecur = act ? (ef[T_ + j] + eb[T_ + j]) : 0.0f;                       // s=1
  float enxt = (act && 2 < S_) ? (ef[2*T_ + j] + eb[2*T_ + j]) : 0.0f;       // s=2
  for (int s=1;s<S_;++s){
    float enew = (act && s+2 < S_) ? (ef[(size_t)(s+2)*T_ + j] + eb[(size_t)(s+2)*T_ + j]) : 0.0f;
    if (act){
      float av[T_];
      #pragma unroll
      for (int i=0;i<T_;++i) av[i] = al2[half][i] + tcol[i];
      float m = fmaxf(
        fmaxf(fmaxf(fmaxf(av[0],av[1]),fmaxf(av[2],av[3])),
              fmaxf(fmaxf(av[4],av[5]),fmaxf(av[6],av[7]))),
        fmaxf(fmaxf(fmaxf(av[8],av[9]),fmaxf(av[10],av[11])),
              fmaxf(fmaxf(av[12],av[13]),fmaxf(fmaxf(av[14],av[15]),av[16]))));
      float s0=0.f,s1=0.f,s2=0.f,s3=0.f;
      #pragma unroll
      for (int i=0;i<16;i+=4){
        s0 += __expf(av[i]-m);   s1 += __expf(av[i+1]-m);
        s2 += __expf(av[i+2]-m); s3 += __expf(av[i+3]-m);
      }
      s0 += __expf(av[16]-m);
      float sum = (s0+s1)+(s2+s3);
      al2[half][j] = m + __logf(sum) + ecur;   // same-wave LDS: program-ordered
    }
    ecur = enxt; enxt = enew;
  }
  if (j == 0){
    float v[T_];
    #pragma unroll
    for (int i=0;i<T_;++i) v[i] = al2[half][i] + end_[i];
    float m = fmaxf(
      fmaxf(fmaxf(fmaxf(v[0],v[1]),fmaxf(v[2],v[3])),
            fmaxf(fmaxf(v[4],v[5]),fmaxf(v[6],v[7]))),
      fmaxf(fmaxf(fmaxf(v[8],v[9]),fmaxf(v[10],v[11])),
            fmaxf(fmaxf(v[12],v[13]),fmaxf(fmaxf(v[14],v[15]),v[16]))));
    float sum = 0.0f;
    #pragma unroll
    for (int i=0;i<T_;++i) sum += __expf(v[i]-m);
    logZ[b] = m + __logf(sum);
  }
}

// ---------- K6: final scalar ----------
__global__ __launch_bounds__(128) void final_kernel(const float* __restrict__ logZ,
    const float* __restrict__ score, float* __restrict__ out){
  int tid = threadIdx.x;
  float v = logZ[tid] - score[tid];
  __shared__ float red[128];
  red[tid] = v; __syncthreads();
  for (int off=64; off; off>>=1){
    if (tid < off) red[tid] += red[tid+off];
    __syncthreads();
  }
  if (tid == 0) out[0] = red[0];
}

extern "C" void kernel_launch(void* const* d_in, const int* in_sizes, int n_in,
                              void* d_out, int out_size, void* d_ws, size_t ws_size,
                              hipStream_t stream) {
  const int*   x       = (const int*)  d_in[0];
  const int*   char_x  = (const int*)  d_in[1];
  const int*   tags    = (const int*)  d_in[2];
  // d_in[3] = mask: constitutively all-ones -> unused
  const float* wemb    = (const float*)d_in[4];
  const float* cemb    = (const float*)d_in[5];
  const float* c2W     = (const float*)d_in[6];
  const float* c2b     = (const float*)d_in[7];
  const float* c3W     = (const float*)d_in[8];
  const float* c3b     = (const float*)d_in[9];
  const float* c4W     = (const float*)d_in[10];
  const float* c4b     = (const float*)d_in[11];
  const float* Wih_f   = (const float*)d_in[12];
  const float* Whh_f   = (const float*)d_in[13];
  const float* b_f     = (const float*)d_in[14];
  const float* Wih_b   = (const float*)d_in[15];
  const float* Whh_b   = (const float*)d_in[16];
  const float* b_b     = (const float*)d_in[17];
  const float* h2tW    = (const float*)d_in[18];
  const float* h2tb    = (const float*)d_in[19];
  const float* crf_s   = (const float*)d_in[20];
  const float* crf_e   = (const float*)d_in[21];
  const float* crf_t   = (const float*)d_in[22];
  float* out = (float*)d_out;

  // ---- workspace layout (bytes) ----
  // pre   (bf16 [2][128][512][512]) 134,217,728 @ 0
  // feats (bf16 [65536][192])        25,165,824 @ 134,217,728  (dead after pre_gemm)
  //   em_f (f32 [128][512][17])       4,456,448 @ 134,217,728  (overlaps dead feats)
  //   em_b (f32 [128][512][17])       4,456,448 @ 138,674,176  (ends 143,130,624)
  // wpk   (bf16 [1024][192])            393,216 @ 159,383,552
  // wpk2  (bf16 [2][512][128])          262,144 @ 159,776,768
  // wem   (bf16 [2][32][128])            16,384 @ 160,038,912
  // score / logZ                        @ 160,055,296 / 160,055,808
  const size_t NEEDED = 160056320ULL;
  if (ws_size < NEEDED) return;   // clean numeric failure instead of GPU fault
  char* wsb = (char*)d_ws;
  bf16*  pre   = (bf16*)(wsb);
  bf16*  feats = (bf16*)(wsb + 134217728);
  float* em_f  = (float*)(wsb + 134217728);
  float* em_b  = (float*)(wsb + 138674176);
  bf16*  wpk   = (bf16*)(wsb + 159383552);
  bf16*  wpk2  = (bf16*)(wsb + 159776768);
  bf16*  wem   = (bf16*)(wsb + 160038912);
  float* score = (float*)(wsb + 160055296);
  float* logZ  = (float*)(wsb + 160055808);

  zero_pad_kernel<<<4352, 256, 0, stream>>>(feats);
  word_emb_kernel<<<32768, 256, 0, stream>>>(x, wemb, feats);
  char_conv_kernel<2><<<6400, 256, 0, stream>>>(char_x, cemb, c2W, c2b, feats, E_);
  char_conv_kernel<3><<<6400, 256, 0, stream>>>(char_x, cemb, c3W, c3b, feats, E_ + NF_);
  char_conv_kernel<4><<<6400, 256, 0, stream>>>(char_x, cemb, c4W, c4b, feats, E_ + 2*NF_);
  wpack_kernel<<<1024, 192, 0, stream>>>(Wih_f, Wih_b, wpk);
  whh_pack_kernel<<<512, 256, 0, stream>>>(Whh_f, Whh_b, wpk2);
  wem_pack_kernel<<<32, 256, 0, stream>>>(h2tW, wem);
  pre_gemm_mfma<<<dim3(512, 8), 256, 0, stream>>>(feats, wpk, b_f, b_b, pre);
  lstm_mfma_kernel<<<16, 512, 0, stream>>>(pre, wpk2, wem, h2tb, em_f, em_b);
  score_kernel<<<128, 256, 0, stream>>>(tags, em_f, em_b, crf_s, crf_e, crf_t, score);
  crf_alpha_kernel<<<64, 64, 0, stream>>>(em_f, em_b, crf_s, crf_e, crf_t, logZ);
  final_kernel<<<1, 128, 0, stream>>>(logZ, score, out);
}

// Round 11
// 1776.209 us; speedup vs baseline: 1.0228x; 1.0228x over previous
//
#include <hip/hip_runtime.h>
#include <hip/hip_bf16.h>

#define B_ 128
#define S_ 512
#define C_ 16
#define E_ 100
#define CE_ 30
#define NF_ 25
#define H_ 128
#define T_ 17
#define LSTM_IN_ 175
#define KP_ 192        // feats K padded to multiple of 32 for MFMA
#define G4_ 512        // 4*H

typedef __hip_bfloat16 bf16;
typedef short bf16x8 __attribute__((ext_vector_type(8)));
typedef float f32x4 __attribute__((ext_vector_type(4)));

// ---------- helpers ----------
__device__ __forceinline__ float bf2f(unsigned short u){
  union { unsigned int i; float f; } v; v.i = ((unsigned int)u) << 16; return v.f;
}
__device__ __forceinline__ float sigm_f(float x){
  float e = __expf(-x);
  return __builtin_amdgcn_rcpf(1.0f + e);
}
__device__ __forceinline__ float tanh_f(float x){
  x = fminf(15.0f, fmaxf(-15.0f, x));
  float e = __expf(-2.0f*x);
  return (1.0f - e) * __builtin_amdgcn_rcpf(1.0f + e);
}
__device__ __forceinline__ short bf16bits(float f){
  bf16 b = __float2bfloat16(f);
  return *(short*)&b;
}

// ---------- K-1: zero the K-pad columns of feats ----------
__global__ __launch_bounds__(256) void zero_pad_kernel(bf16* __restrict__ feats){
  int task = blockIdx.x*256 + threadIdx.x;      // 65536*17 = 1,114,112 exact
  int word = task / 17;
  int col = LSTM_IN_ + (task - word*17);        // 175..191
  feats[(size_t)word*KP_ + col] = __float2bfloat16(0.0f);
}

// ---------- K0: word embedding gather -> feats[:, 0:100] ----------
__global__ __launch_bounds__(256) void word_emb_kernel(const int* __restrict__ x,
    const float* __restrict__ wemb, bf16* __restrict__ feats){
  int word = blockIdx.x*2 + (threadIdx.x>>7);
  int e = threadIdx.x & 127;
  if (e < E_) feats[(size_t)word*KP_ + e] = __float2bfloat16(wemb[(size_t)x[word]*E_ + e]);
}

// ---------- K1: char conv (f32, stride-192 out) ----------
template<int KW>
__global__ __launch_bounds__(256) void char_conv_kernel(const int* __restrict__ char_x,
    const float* __restrict__ cemb, const float* __restrict__ W,
    const float* __restrict__ bias, bf16* __restrict__ feats, int out_off){
  int task = blockIdx.x*256 + threadIdx.x;     // 65536*25 tasks
  int word = task / NF_;
  int fi = task - word*NF_;
  const int* cx = char_x + word*C_;
  float w[KW*CE_];
  #pragma unroll
  for (int i=0;i<KW*CE_;++i) w[i] = W[fi*CE_*KW + i];   // [fi][e][dx]
  const int NP = C_ - KW + 1;
  float acc[C_ - KW + 1];
  #pragma unroll
  for (int p=0;p<NP;++p) acc[p] = 0.0f;
  #pragma unroll
  for (int c=0;c<C_;++c){
    int ci = cx[c];
    const float* ce = cemb + ci*CE_;
    #pragma unroll
    for (int e=0;e<CE_;++e){
      float v = ce[e];
      #pragma unroll
      for (int dx=0;dx<KW;++dx){
        int p = c - dx;
        if (p >= 0 && p < NP) acc[p] = fmaf(v, w[e*KW+dx], acc[p]);
      }
    }
  }
  float m = acc[0];
  #pragma unroll
  for (int p=1;p<NP;++p) m = fmaxf(m, acc[p]);
  feats[(size_t)word*KP_ + out_off + fi] = __float2bfloat16(fmaxf(0.0f, m + bias[fi]));
}

// ---------- W_ih f32 [512][175] (x2 dirs) -> bf16 [1024][192] zero-padded ----------
__global__ __launch_bounds__(192) void wpack_kernel(const float* __restrict__ Wf,
    const float* __restrict__ Wb, bf16* __restrict__ wpk){
  int g = blockIdx.x;            // 0..1023
  int k = threadIdx.x;           // 0..191
  float v = 0.0f;
  if (k < LSTM_IN_) v = (g < 512) ? Wf[g*LSTM_IN_ + k] : Wb[(g-512)*LSTM_IN_ + k];
  wpk[(size_t)g*KP_ + k] = __float2bfloat16(v);
}

// ---------- Whh f32 [512][128] (x2 dirs) -> bf16 [2][512][128] ----------
__global__ __launch_bounds__(256) void whh_pack_kernel(const float* __restrict__ Wf,
    const float* __restrict__ Wb, bf16* __restrict__ wpk2){
  int idx = blockIdx.x*256 + threadIdx.x;   // 131072 exact (512 blocks)
  int dir = idx >> 16;
  int rem = idx & 65535;
  const float* W = dir ? Wb : Wf;
  wpk2[idx] = __float2bfloat16(W[rem]);
}

// ---------- K2: pre = feats @ W_ih^T + b  (MFMA bf16, global_load_lds, dbuf) ----------
__global__ __launch_bounds__(256, 3) void pre_gemm_mfma(const bf16* __restrict__ feats,
    const bf16* __restrict__ wpk, const float* __restrict__ bf_,
    const float* __restrict__ bb_, bf16* __restrict__ pre){
  __shared__ __align__(16) short lds[16384];   // 32KB: 2 x (A 4096 + B 4096); reused as C-stage
  int br = blockIdx.x;           // 0..511
  int bc = blockIdx.y;           // 0..7
  int dir = bc >> 2;
  int g0 = (bc & 3) * 128;
  const float* bias = dir ? bb_ : bf_;
  int tid = threadIdx.x;
  int wave = tid >> 6, lane = tid & 63;
  int wr = wave >> 1, wc = wave & 1;
  int lrow = lane & 15, lkb = lane >> 4;
  const bf16* Arow = feats + (size_t)br*128*KP_;
  const bf16* Brow = wpk + (size_t)(dir*512 + g0)*KP_;

  auto stage = [&](int bufbase, int k0){
    int s0 = wave*2, s1 = s0 + 1;
    __builtin_amdgcn_global_load_lds(
        (const __attribute__((address_space(1))) void*)(Arow + (size_t)(s0*16 + lrow)*KP_ + k0 + lkb*8),
        (__attribute__((address_space(3))) void*)&lds[bufbase + s0*512], 16, 0, 0);
    __builtin_amdgcn_global_load_lds(
        (const __attribute__((address_space(1))) void*)(Arow + (size_t)(s1*16 + lrow)*KP_ + k0 + lkb*8),
        (__attribute__((address_space(3))) void*)&lds[bufbase + s1*512], 16, 0, 0);
    __builtin_amdgcn_global_load_lds(
        (const __attribute__((address_space(1))) void*)(Brow + (size_t)(s0*16 + lrow)*KP_ + k0 + lkb*8),
        (__attribute__((address_space(3))) void*)&lds[bufbase + 4096 + s0*512], 16, 0, 0);
    __builtin_amdgcn_global_load_lds(
        (const __attribute__((address_space(1))) void*)(Brow + (size_t)(s1*16 + lrow)*KP_ + k0 + lkb*8),
        (__attribute__((address_space(3))) void*)&lds[bufbase + 4096 + s1*512], 16, 0, 0);
  };

  f32x4 acc[4][4];
  #pragma unroll
  for (int i=0;i<4;++i)
    #pragma unroll
    for (int j=0;j<4;++j) acc[i][j] = (f32x4){0.f,0.f,0.f,0.f};

  stage(0, 0);
  __syncthreads();
  int cur = 0;
  for (int t = 0; t < 6; ++t){
    if (t < 5) stage((cur^1)*8192, (t+1)*32);
    const short* A  = &lds[cur*8192];
    const short* Bv = &lds[cur*8192 + 4096];
    bf16x8 af[4], bfr[4];
    #pragma unroll
    for (int i=0;i<4;++i) af[i]  = *(const bf16x8*)&A[(wr*4+i)*512 + lane*8];
    #pragma unroll
    for (int j=0;j<4;++j) bfr[j] = *(const bf16x8*)&Bv[(wc*4+j)*512 + lane*8];
    #pragma unroll
    for (int i=0;i<4;++i)
      #pragma unroll
      for (int j=0;j<4;++j)
        acc[i][j] = __builtin_amdgcn_mfma_f32_16x16x32_bf16(af[i], bfr[j], acc[i][j], 0, 0, 0);
    __syncthreads();
    cur ^= 1;
  }

  // epilogue: swizzled C-stage in LDS, then coalesced 16B global stores
  int col_l = lane & 15;
  int row_l = (lane >> 4) * 4;
  float bias_v[4];
  #pragma unroll
  for (int j=0;j<4;++j) bias_v[j] = bias[g0 + wc*64 + j*16 + col_l];
  #pragma unroll
  for (int i=0;i<4;++i){
    #pragma unroll
    for (int q=0;q<4;++q){
      int r = wr*64 + i*16 + row_l + q;
      #pragma unroll
      for (int j=0;j<4;++j){
        int cbyte = (wc*64 + j*16 + col_l) * 2;
        int addr = r*256 + (cbyte ^ ((r & 7) << 4));
        *(short*)((char*)lds + addr) = bf16bits(acc[i][j][q] + bias_v[j]);
      }
    }
  }
  __syncthreads();
  int r = tid >> 1, half = tid & 1;
  int word = br*128 + r;
  int bidx = word >> 9, sidx = word & 511;
  bf16* dst = pre + ((size_t)(dir*B_ + bidx)*S_ + sidx)*G4_ + g0 + half*64;
  #pragma unroll
  for (int k=0;k<8;++k){
    int boff = (half*128 + k*16) ^ ((r & 7) << 4);
    int4 v = *(const int4*)((const char*)lds + r*256 + boff);
    *(int4*)((char*)dst + k*16) = v;
  }
}

// ---------- K3: LSTM recurrence via MFMA; pointer-walk loads/stores (R11 change) ----------
// block = (dir, batch-group of 16). 16 blocks x 512 threads (8 waves).
__global__ __launch_bounds__(512) void lstm_mfma_kernel(
    const bf16* __restrict__ pre, const bf16* __restrict__ wpk2,
    bf16* __restrict__ hs){
  int blk = blockIdx.x;           // 0..15
  int dir = blk & 1;
  int bg  = blk >> 1;             // 0..7
  int tid = threadIdx.x;
  int w = tid >> 6, l = tid & 63;
  int lm = l & 15, lk = l >> 4;
  int gcol = 16*w + lm;

  bf16x8 Bf[4][4];
  {
    const bf16* Wd = wpk2 + (size_t)dir*512*128;
    #pragma unroll
    for (int ct=0; ct<4; ++ct)
      #pragma unroll
      for (int kk=0; kk<4; ++kk)
        Bf[ct][kk] = *(const bf16x8*)(Wd + (ct*128 + gcol)*128 + 32*kk + lk*8);
  }

  __shared__ __align__(16) short h_sh[2][2048];
  for (int i = tid; i < 1024; i += 512) ((int*)h_sh[0])[i] = 0;

  float c[4] = {0.f, 0.f, 0.f, 0.f};
  const bf16* preB = pre + (size_t)(dir*B_ + bg*16) * (S_*G4_);
  bf16* hsB = hs + (size_t)(dir*B_ + bg*16) * (S_*H_);
  int sd  = dir ? -1 : 1;
  int sdG = sd * G4_;             // pre walk (elements)
  int sdH = sd * H_;              // hs walk (elements)
  int idx0 = dir ? (S_-1) : 0;

  const bf16 *p0 = preB + ((size_t)(lk*4+0)*S_ + idx0)*G4_ + gcol;
  const bf16 *p1 = preB + ((size_t)(lk*4+1)*S_ + idx0)*G4_ + gcol;
  const bf16 *p2 = preB + ((size_t)(lk*4+2)*S_ + idx0)*G4_ + gcol;
  const bf16 *p3 = preB + ((size_t)(lk*4+3)*S_ + idx0)*G4_ + gcol;
  bf16 *h0 = hsB + ((size_t)(lk*4+0)*S_ + idx0)*H_ + gcol;
  bf16 *h1 = hsB + ((size_t)(lk*4+1)*S_ + idx0)*H_ + gcol;
  bf16 *h2p = hsB + ((size_t)(lk*4+2)*S_ + idx0)*H_ + gcol;
  bf16 *h3 = hsB + ((size_t)(lk*4+3)*S_ + idx0)*H_ + gcol;

  unsigned short pfA[16], pfB[16];
  auto LOADPF = [&](unsigned short (&pf)[16], bool g){
    if (g){
      pf[0]  = *(const unsigned short*)(p0);     pf[1]  = *(const unsigned short*)(p0+128);
      pf[2]  = *(const unsigned short*)(p0+256); pf[3]  = *(const unsigned short*)(p0+384);
      pf[4]  = *(const unsigned short*)(p1);     pf[5]  = *(const unsigned short*)(p1+128);
      pf[6]  = *(const unsigned short*)(p1+256); pf[7]  = *(const unsigned short*)(p1+384);
      pf[8]  = *(const unsigned short*)(p2);     pf[9]  = *(const unsigned short*)(p2+128);
      pf[10] = *(const unsigned short*)(p2+256); pf[11] = *(const unsigned short*)(p2+384);
      pf[12] = *(const unsigned short*)(p3);     pf[13] = *(const unsigned short*)(p3+128);
      pf[14] = *(const unsigned short*)(p3+256); pf[15] = *(const unsigned short*)(p3+384);
    }
    p0 += sdG; p1 += sdG; p2 += sdG; p3 += sdG;
  };

  auto STEP = [&](unsigned short (&pfuse)[16], int s, const short* src, short* dst){
    f32x4 a0, a1, a2, a3;
    #pragma unroll
    for (int q=0;q<4;++q){
      a0[q] = bf2f(pfuse[q*4+0]);
      a1[q] = bf2f(pfuse[q*4+1]);
      a2[q] = bf2f(pfuse[q*4+2]);
      a3[q] = bf2f(pfuse[q*4+3]);
    }
    LOADPF(pfuse, s+2 < S_);      // prefetch, stays in flight across raw barrier
    #pragma unroll
    for (int kk=0;kk<4;++kk){
      int sc = ((4*kk + lk) ^ lm) & 15;
      bf16x8 af = *(const bf16x8*)((const char*)src + lm*256 + sc*16);
      a0 = __builtin_amdgcn_mfma_f32_16x16x32_bf16(af, Bf[0][kk], a0, 0, 0, 0);
      a1 = __builtin_amdgcn_mfma_f32_16x16x32_bf16(af, Bf[1][kk], a1, 0, 0, 0);
      a2 = __builtin_amdgcn_mfma_f32_16x16x32_bf16(af, Bf[2][kk], a2, 0, 0, 0);
      a3 = __builtin_amdgcn_mfma_f32_16x16x32_bf16(af, Bf[3][kk], a3, 0, 0, 0);
    }
    float hv[4];
    #pragma unroll
    for (int q=0;q<4;++q){
      float iv = sigm_f(a0[q]);
      float fv = sigm_f(a1[q]);
      float gv = tanh_f(a2[q]);
      float ov = sigm_f(a3[q]);
      c[q] = fmaf(fv, c[q], iv*gv);
      hv[q] = ov * tanh_f(c[q]);
    }
    #pragma unroll
    for (int q=0;q<4;++q){
      int b = lk*4 + q;
      int scw = ((gcol >> 3) ^ b) & 15;
      *(short*)((char*)dst + b*256 + scw*16 + (gcol & 7)*2) = bf16bits(hv[q]);
    }
    *h0 = __float2bfloat16(hv[0]); h0 += sdH;
    *h1 = __float2bfloat16(hv[1]); h1 += sdH;
    *h2p = __float2bfloat16(hv[2]); h2p += sdH;
    *h3 = __float2bfloat16(hv[3]); h3 += sdH;
    asm volatile("s_waitcnt lgkmcnt(0)" ::: "memory");
    __builtin_amdgcn_s_barrier();
    asm volatile("" ::: "memory");
  };

  __syncthreads();                // h_sh[0] zero-init visible
  LOADPF(pfA, true);
  LOADPF(pfB, true);
  for (int s = 0; s < S_; s += 2){
    STEP(pfA, s,   h_sh[0], h_sh[1]);
    STEP(pfB, s+1, h_sh[1], h_sh[0]);
  }
}

// ---------- K4: emissions ----------
__global__ __launch_bounds__(256) void emis_kernel(const bf16* __restrict__ hs,
    const float* __restrict__ W, const float* __restrict__ bias, float* __restrict__ em){
  int task = blockIdx.x*256 + threadIdx.x;     // 65536*17 tasks
  int word = task / T_;
  int t = task - word*T_;
  const ushort4* hf = (const ushort4*)(hs + (size_t)word*H_);
  const ushort4* hb = (const ushort4*)(hs + (size_t)(B_*S_ + word)*H_);
  const float* w0 = W + t*2*H_;
  float acc = bias[t];
  #pragma unroll
  for (int j4=0;j4<32;++j4){
    ushort4 u = hf[j4];
    float4 w4 = *(const float4*)&w0[j4*4];
    acc = fmaf(bf2f(u.x),w4.x,acc); acc = fmaf(bf2f(u.y),w4.y,acc);
    acc = fmaf(bf2f(u.z),w4.z,acc); acc = fmaf(bf2f(u.w),w4.w,acc);
  }
  #pragma unroll
  for (int j4=0;j4<32;++j4){
    ushort4 u = hb[j4];
    float4 w4 = *(const float4*)&w0[H_ + j4*4];
    acc = fmaf(bf2f(u.x),w4.x,acc); acc = fmaf(bf2f(u.y),w4.y,acc);
    acc = fmaf(bf2f(u.z),w4.z,acc); acc = fmaf(bf2f(u.w),w4.w,acc);
  }
  em[(size_t)word*T_ + t] = acc;
}

// ---------- K5a: gold-path score ----------
__global__ __launch_bounds__(256) void score_kernel(const int* __restrict__ tags,
    const float* __restrict__ em, const float* __restrict__ start,
    const float* __restrict__ end_, const float* __restrict__ trans,
    float* __restrict__ score){
  int b = blockIdx.x;
  int tid = threadIdx.x;
  const int* tg = tags + b*S_;
  const float* eb = em + (size_t)b*S_*T_;
  float s = 0.0f;
  for (int t = tid; t < S_; t += 256){
    int cur = tg[t];
    s += eb[(size_t)t*T_ + cur];
    if (t > 0) s += trans[tg[t-1]*T_ + cur];
  }
  if (tid == 0) s += start[tg[0]] + end_[tg[S_-1]];
  __shared__ float red[256];
  red[tid] = s; __syncthreads();
  for (int off=128; off; off>>=1){
    if (tid < off) red[tid] += red[tid+off];
    __syncthreads();
  }
  if (tid == 0) score[b] = red[0];
}

// ---------- K5b: CRF forward recursion (single wave: no barriers) ----------
__global__ __launch_bounds__(64) void crf_alpha_kernel(const float* __restrict__ em,
    const float* __restrict__ start, const float* __restrict__ end_,
    const float* __restrict__ trans, float* __restrict__ logZ){
  int b = blockIdx.x;
  int j = threadIdx.x;          // lane j owns tag j (j<17); block = ONE wave
  __shared__ float al[T_];
  const float* eb = em + (size_t)b*S_*T_;
  float tcol[T_];
  if (j < T_){
    #pragma unroll
    for (int i=0;i<T_;++i) tcol[i] = trans[i*T_ + j];
    al[j] = start[j] + eb[j];
  }
  float e_cur = (j < T_) ? eb[T_ + j] : 0.0f;
  for (int s=1;s<S_;++s){
    float e_nxt = (j < T_ && s+1 < S_) ? eb[(size_t)(s+1)*T_ + j] : 0.0f;
    if (j < T_){
      float av[T_];
      float m = -1e30f;
      #pragma unroll
      for (int i=0;i<T_;++i){ av[i] = al[i] + tcol[i]; m = fmaxf(m, av[i]); }
      float sum = 0.0f;
      #pragma unroll
      for (int i=0;i<T_;++i) sum += __expf(av[i]-m);
      float nv = m + __logf(sum) + e_cur;
      al[j] = nv;                 // same-wave LDS ops are program-ordered
    }
    e_cur = e_nxt;
  }
  if (j == 0){
    float m = -1e30f;
    float v[T_];
    #pragma unroll
    for (int i=0;i<T_;++i){ v[i] = al[i] + end_[i]; m = fmaxf(m, v[i]); }
    float sum = 0.0f;
    #pragma unroll
    for (int i=0;i<T_;++i) sum += __expf(v[i]-m);
    logZ[b] = m + __logf(sum);
  }
}

// ---------- K6: final scalar ----------
__global__ __launch_bounds__(128) void final_kernel(const float* __restrict__ logZ,
    const float* __restrict__ score, float* __restrict__ out){
  int tid = threadIdx.x;
  float v = logZ[tid] - score[tid];
  __shared__ float red[128];
  red[tid] = v; __syncthreads();
  for (int off=64; off; off>>=1){
    if (tid < off) red[tid] += red[tid+off];
    __syncthreads();
  }
  if (tid == 0) out[0] = red[0];
}

extern "C" void kernel_launch(void* const* d_in, const int* in_sizes, int n_in,
                              void* d_out, int out_size, void* d_ws, size_t ws_size,
                              hipStream_t stream) {
  const int*   x       = (const int*)  d_in[0];
  const int*   char_x  = (const int*)  d_in[1];
  const int*   tags    = (const int*)  d_in[2];
  // d_in[3] = mask: constitutively all-ones -> unused
  const float* wemb    = (const float*)d_in[4];
  const float* cemb    = (const float*)d_in[5];
  const float* c2W     = (const float*)d_in[6];
  const float* c2b     = (const float*)d_in[7];
  const float* c3W     = (const float*)d_in[8];
  const float* c3b     = (const float*)d_in[9];
  const float* c4W     = (const float*)d_in[10];
  const float* c4b     = (const float*)d_in[11];
  const float* Wih_f   = (const float*)d_in[12];
  const float* Whh_f   = (const float*)d_in[13];
  const float* b_f     = (const float*)d_in[14];
  const float* Wih_b   = (const float*)d_in[15];
  const float* Whh_b   = (const float*)d_in[16];
  const float* b_b     = (const float*)d_in[17];
  const float* h2tW    = (const float*)d_in[18];
  const float* h2tb    = (const float*)d_in[19];
  const float* crf_s   = (const float*)d_in[20];
  const float* crf_e   = (const float*)d_in[21];
  const float* crf_t   = (const float*)d_in[22];
  float* out = (float*)d_out;

  // ---- workspace layout (bytes) — R9-identical ----
  // pre   (bf16 [2][128][512][512]) 134,217,728 @ 0
  // feats (bf16 [65536][192])        25,165,824 @ 134,217,728  (dead after pre_gemm)
  // wpk   (bf16 [1024][192])            393,216 @ 159,383,552  (dead after pre_gemm)
  // hs    (bf16 [2][65536][128])     33,554,432 @ 134,217,728  (overlaps dead feats+wpk)
  // em    (f32  [65536][17])          4,456,448 @ 0            (overlaps dead pre)
  // score / logZ                      @ 167,772,160 / 167,772,672
  // wpk2  (bf16 [2][512][128])          262,144 @ 167,773,184
  const size_t NEEDED = 168035328ULL;
  if (ws_size < NEEDED) return;   // clean numeric failure instead of GPU fault
  char* wsb = (char*)d_ws;
  bf16*  pre   = (bf16*)(wsb);
  bf16*  feats = (bf16*)(wsb + 134217728);
  bf16*  wpk   = (bf16*)(wsb + 159383552);
  bf16*  hs    = (bf16*)(wsb + 134217728);
  float* em    = (float*)(wsb);
  float* score = (float*)(wsb + 167772160);
  float* logZ  = (float*)(wsb + 167772672);
  bf16*  wpk2  = (bf16*)(wsb + 167773184);

  zero_pad_kernel<<<4352, 256, 0, stream>>>(feats);
  word_emb_kernel<<<32768, 256, 0, stream>>>(x, wemb, feats);
  char_conv_kernel<2><<<6400, 256, 0, stream>>>(char_x, cemb, c2W, c2b, feats, E_);
  char_conv_kernel<3><<<6400, 256, 0, stream>>>(char_x, cemb, c3W, c3b, feats, E_ + NF_);
  char_conv_kernel<4><<<6400, 256, 0, stream>>>(char_x, cemb, c4W, c4b, feats, E_ + 2*NF_);
  wpack_kernel<<<1024, 192, 0, stream>>>(Wih_f, Wih_b, wpk);
  whh_pack_kernel<<<512, 256, 0, stream>>>(Whh_f, Whh_b, wpk2);
  pre_gemm_mfma<<<dim3(512, 8), 256, 0, stream>>>(feats, wpk, b_f, b_b, pre);
  lstm_mfma_kernel<<<16, 512, 0, stream>>>(pre, wpk2, hs);
  emis_kernel<<<4352, 256, 0, stream>>>(hs, h2tW, h2tb, em);
  score_kernel<<<128, 256, 0, stream>>>(tags, em, crf_s, crf_e, crf_t, score);
  crf_alpha_kernel<<<128, 64, 0, stream>>>(em, crf_s, crf_e, crf_t, logZ);
  final_kernel<<<1, 128, 0, stream>>>(logZ, score, out);
}

// Round 13
// 1617.359 us; speedup vs baseline: 1.1232x; 1.0982x over previous
//
#include <hip/hip_runtime.h>
#include <hip/hip_bf16.h>

#define B_ 128
#define S_ 512
#define C_ 16
#define E_ 100
#define CE_ 30
#define NF_ 25
#define H_ 128
#define T_ 17
#define LSTM_IN_ 175
#define KP_ 192        // feats K padded to multiple of 32 for MFMA
#define G4_ 512        // 4*H

typedef __hip_bfloat16 bf16;
typedef short bf16x8 __attribute__((ext_vector_type(8)));
typedef float f32x4 __attribute__((ext_vector_type(4)));

// ---------- helpers ----------
__device__ __forceinline__ float bf2f(unsigned short u){
  union { unsigned int i; float f; } v; v.i = ((unsigned int)u) << 16; return v.f;
}
__device__ __forceinline__ float sigm_f(float x){
  float e = __expf(-x);
  return __builtin_amdgcn_rcpf(1.0f + e);
}
__device__ __forceinline__ float tanh_f(float x){
  x = fminf(15.0f, fmaxf(-15.0f, x));
  float e = __expf(-2.0f*x);
  return (1.0f - e) * __builtin_amdgcn_rcpf(1.0f + e);
}
__device__ __forceinline__ short bf16bits(float f){
  bf16 b = __float2bfloat16(f);
  return *(short*)&b;
}

// ---------- K-1: zero the K-pad columns of feats ----------
__global__ __launch_bounds__(256) void zero_pad_kernel(bf16* __restrict__ feats){
  int task = blockIdx.x*256 + threadIdx.x;      // 65536*17 = 1,114,112 exact
  int word = task / 17;
  int col = LSTM_IN_ + (task - word*17);        // 175..191
  feats[(size_t)word*KP_ + col] = __float2bfloat16(0.0f);
}

// ---------- K0: word embedding gather -> feats[:, 0:100] ----------
__global__ __launch_bounds__(256) void word_emb_kernel(const int* __restrict__ x,
    const float* __restrict__ wemb, bf16* __restrict__ feats){
  int word = blockIdx.x*2 + (threadIdx.x>>7);
  int e = threadIdx.x & 127;
  if (e < E_) feats[(size_t)word*KP_ + e] = __float2bfloat16(wemb[(size_t)x[word]*E_ + e]);
}

// ---------- K1: char conv (f32, stride-192 out) ----------
template<int KW>
__global__ __launch_bounds__(256) void char_conv_kernel(const int* __restrict__ char_x,
    const float* __restrict__ cemb, const float* __restrict__ W,
    const float* __restrict__ bias, bf16* __restrict__ feats, int out_off){
  int task = blockIdx.x*256 + threadIdx.x;     // 65536*25 tasks
  int word = task / NF_;
  int fi = task - word*NF_;
  const int* cx = char_x + word*C_;
  float w[KW*CE_];
  #pragma unroll
  for (int i=0;i<KW*CE_;++i) w[i] = W[fi*CE_*KW + i];   // [fi][e][dx]
  const int NP = C_ - KW + 1;
  float acc[C_ - KW + 1];
  #pragma unroll
  for (int p=0;p<NP;++p) acc[p] = 0.0f;
  #pragma unroll
  for (int c=0;c<C_;++c){
    int ci = cx[c];
    const float* ce = cemb + ci*CE_;
    #pragma unroll
    for (int e=0;e<CE_;++e){
      float v = ce[e];
      #pragma unroll
      for (int dx=0;dx<KW;++dx){
        int p = c - dx;
        if (p >= 0 && p < NP) acc[p] = fmaf(v, w[e*KW+dx], acc[p]);
      }
    }
  }
  float m = acc[0];
  #pragma unroll
  for (int p=1;p<NP;++p) m = fmaxf(m, acc[p]);
  feats[(size_t)word*KP_ + out_off + fi] = __float2bfloat16(fmaxf(0.0f, m + bias[fi]));
}

// ---------- W_ih f32 [512][175] (x2 dirs) -> bf16 [1024][192] zero-padded ----------
__global__ __launch_bounds__(192) void wpack_kernel(const float* __restrict__ Wf,
    const float* __restrict__ Wb, bf16* __restrict__ wpk){
  int g = blockIdx.x;            // 0..1023
  int k = threadIdx.x;           // 0..191
  float v = 0.0f;
  if (k < LSTM_IN_) v = (g < 512) ? Wf[g*LSTM_IN_ + k] : Wb[(g-512)*LSTM_IN_ + k];
  wpk[(size_t)g*KP_ + k] = __float2bfloat16(v);
}

// ---------- K2: pre = feats @ W_ih^T + b  (MFMA bf16, global_load_lds, dbuf) ----------
__global__ __launch_bounds__(256, 3) void pre_gemm_mfma(const bf16* __restrict__ feats,
    const bf16* __restrict__ wpk, const float* __restrict__ bf_,
    const float* __restrict__ bb_, bf16* __restrict__ pre){
  __shared__ __align__(16) short lds[16384];   // 32KB: 2 x (A 4096 + B 4096); reused as C-stage
  int br = blockIdx.x;           // 0..511
  int bc = blockIdx.y;           // 0..7
  int dir = bc >> 2;
  int g0 = (bc & 3) * 128;
  const float* bias = dir ? bb_ : bf_;
  int tid = threadIdx.x;
  int wave = tid >> 6, lane = tid & 63;
  int wr = wave >> 1, wc = wave & 1;
  int lrow = lane & 15, lkb = lane >> 4;
  const bf16* Arow = feats + (size_t)br*128*KP_;
  const bf16* Brow = wpk + (size_t)(dir*512 + g0)*KP_;

  auto stage = [&](int bufbase, int k0){
    int s0 = wave*2, s1 = s0 + 1;
    __builtin_amdgcn_global_load_lds(
        (const __attribute__((address_space(1))) void*)(Arow + (size_t)(s0*16 + lrow)*KP_ + k0 + lkb*8),
        (__attribute__((address_space(3))) void*)&lds[bufbase + s0*512], 16, 0, 0);
    __builtin_amdgcn_global_load_lds(
        (const __attribute__((address_space(1))) void*)(Arow + (size_t)(s1*16 + lrow)*KP_ + k0 + lkb*8),
        (__attribute__((address_space(3))) void*)&lds[bufbase + s1*512], 16, 0, 0);
    __builtin_amdgcn_global_load_lds(
        (const __attribute__((address_space(1))) void*)(Brow + (size_t)(s0*16 + lrow)*KP_ + k0 + lkb*8),
        (__attribute__((address_space(3))) void*)&lds[bufbase + 4096 + s0*512], 16, 0, 0);
    __builtin_amdgcn_global_load_lds(
        (const __attribute__((address_space(1))) void*)(Brow + (size_t)(s1*16 + lrow)*KP_ + k0 + lkb*8),
        (__attribute__((address_space(3))) void*)&lds[bufbase + 4096 + s1*512], 16, 0, 0);
  };

  f32x4 acc[4][4];
  #pragma unroll
  for (int i=0;i<4;++i)
    #pragma unroll
    for (int j=0;j<4;++j) acc[i][j] = (f32x4){0.f,0.f,0.f,0.f};

  stage(0, 0);
  __syncthreads();
  int cur = 0;
  for (int t = 0; t < 6; ++t){
    if (t < 5) stage((cur^1)*8192, (t+1)*32);
    const short* A  = &lds[cur*8192];
    const short* Bv = &lds[cur*8192 + 4096];
    bf16x8 af[4], bfr[4];
    #pragma unroll
    for (int i=0;i<4;++i) af[i]  = *(const bf16x8*)&A[(wr*4+i)*512 + lane*8];
    #pragma unroll
    for (int j=0;j<4;++j) bfr[j] = *(const bf16x8*)&Bv[(wc*4+j)*512 + lane*8];
    #pragma unroll
    for (int i=0;i<4;++i)
      #pragma unroll
      for (int j=0;j<4;++j)
        acc[i][j] = __builtin_amdgcn_mfma_f32_16x16x32_bf16(af[i], bfr[j], acc[i][j], 0, 0, 0);
    __syncthreads();
    cur ^= 1;
  }

  // epilogue: swizzled C-stage in LDS, then coalesced 16B global stores
  int col_l = lane & 15;
  int row_l = (lane >> 4) * 4;
  float bias_v[4];
  #pragma unroll
  for (int j=0;j<4;++j) bias_v[j] = bias[g0 + wc*64 + j*16 + col_l];
  #pragma unroll
  for (int i=0;i<4;++i){
    #pragma unroll
    for (int q=0;q<4;++q){
      int r = wr*64 + i*16 + row_l + q;
      #pragma unroll
      for (int j=0;j<4;++j){
        int cbyte = (wc*64 + j*16 + col_l) * 2;
        int addr = r*256 + (cbyte ^ ((r & 7) << 4));
        *(short*)((char*)lds + addr) = bf16bits(acc[i][j][q] + bias_v[j]);
      }
    }
  }
  __syncthreads();
  int r = tid >> 1, half = tid & 1;
  int word = br*128 + r;
  int bidx = word >> 9, sidx = word & 511;
  bf16* dst = pre + ((size_t)(dir*B_ + bidx)*S_ + sidx)*G4_ + g0 + half*64;
  #pragma unroll
  for (int k=0;k<8;++k){
    int boff = (half*128 + k*16) ^ ((r & 7) << 4);
    int4 v = *(const int4*)((const char*)lds + r*256 + boff);
    *(int4*)((char*)dst + k*16) = v;
  }
}

// ---------- K3: LSTM recurrence, VALU, all 256 CUs; Whh pinned in VGPRs ----------
// 1 block per (dir, batch). 512 threads; thread g owns gate g. 2 raw barriers/step.
__global__ __launch_bounds__(512, 2) void lstm_valu_kernel(
    const bf16* __restrict__ pre, const float* __restrict__ Whh_f,
    const float* __restrict__ Whh_b, bf16* __restrict__ hs){
  int blk = blockIdx.x;          // 0..255
  int dir = blk & 1;
  int b = blk >> 1;
  int g = threadIdx.x;           // 0..511
  const float* Whh = dir ? Whh_b : Whh_f;
  f32x4 w4[32];                  // Whh row, 128 VGPRs, pinned resident (ext-vector: asm-legal)
  #pragma unroll
  for (int i=0;i<32;++i){
    w4[i] = *(const f32x4*)(Whh + g*H_ + 4*i);
    asm volatile("" : "+v"(w4[i]));
  }
  __shared__ __align__(16) float h_lds[H_];
  __shared__ float gates[G4_];
  if (g < H_) h_lds[g] = 0.0f;
  __syncthreads();
  const bf16* preB = pre + ((size_t)dir*B_ + b)*S_*G4_;
  bf16* hsB = hs + ((size_t)dir*B_ + b)*S_*H_;
  float c = 0.0f;
  int sect = g >> 7;             // 0:i 1:f 2:g 3:o  (wave-uniform)
  unsigned short u0 = *(const unsigned short*)(preB + (size_t)(dir ? (S_-1) : 0)*G4_ + g);
  unsigned short u1 = *(const unsigned short*)(preB + (size_t)(dir ? (S_-2) : 1)*G4_ + g);
  for (int s=0;s<S_;++s){
    int idx = dir ? (S_-1-s) : s;
    float pr = bf2f(u0);
    u0 = u1;
    if (s+2 < S_){
      int idx2 = dir ? (S_-3-s) : (s+2);
      u1 = *(const unsigned short*)(preB + (size_t)idx2*G4_ + g);   // stays in flight
    }
    float a0=0.f, a1=0.f, a2=0.f, a3=0.f;      // 4 independent chains
    const f32x4* hp = (const f32x4*)h_lds;
    #pragma unroll
    for (int k=0;k<32;++k){
      f32x4 hk = hp[k];                         // LDS broadcast, 16B
      f32x4 wk = w4[k];
      a0 = fmaf(wk[0], hk[0], a0);
      a1 = fmaf(wk[1], hk[1], a1);
      a2 = fmaf(wk[2], hk[2], a2);
      a3 = fmaf(wk[3], hk[3], a3);
    }
    float acc = pr + ((a0+a1)+(a2+a3));
    float a = (sect == 2) ? tanh_f(acc) : sigm_f(acc);
    gates[g] = a;
    asm volatile("s_waitcnt lgkmcnt(0)" ::: "memory");   // gates-write landed (LDS only)
    __builtin_amdgcn_s_barrier();                        // B1: gates visible
    asm volatile("" ::: "memory");
    if (g < H_){                                         // wave-uniform (waves 0-1)
      float iv = gates[g];
      float fv = gates[g+128];
      float gv = gates[g+256];
      float ov = gates[g+384];
      c = fmaf(fv, c, iv*gv);
      float hn = ov * tanh_f(c);
      h_lds[g] = hn;
      hsB[(size_t)idx*H_ + g] = __float2bfloat16(hn);
    }
    asm volatile("s_waitcnt lgkmcnt(0)" ::: "memory");   // h-write landed (LDS only)
    __builtin_amdgcn_s_barrier();                        // B2: new h visible
    asm volatile("" ::: "memory");
  }
}

// ---------- K4: emissions ----------
__global__ __launch_bounds__(256) void emis_kernel(const bf16* __restrict__ hs,
    const float* __restrict__ W, const float* __restrict__ bias, float* __restrict__ em){
  int task = blockIdx.x*256 + threadIdx.x;     // 65536*17 tasks
  int word = task / T_;
  int t = task - word*T_;
  const ushort4* hf = (const ushort4*)(hs + (size_t)word*H_);
  const ushort4* hb = (const ushort4*)(hs + (size_t)(B_*S_ + word)*H_);
  const float* w0 = W + t*2*H_;
  float acc = bias[t];
  #pragma unroll
  for (int j4=0;j4<32;++j4){
    ushort4 u = hf[j4];
    float4 w4 = *(const float4*)&w0[j4*4];
    acc = fmaf(bf2f(u.x),w4.x,acc); acc = fmaf(bf2f(u.y),w4.y,acc);
    acc = fmaf(bf2f(u.z),w4.z,acc); acc = fmaf(bf2f(u.w),w4.w,acc);
  }
  #pragma unroll
  for (int j4=0;j4<32;++j4){
    ushort4 u = hb[j4];
    float4 w4 = *(const float4*)&w0[H_ + j4*4];
    acc = fmaf(bf2f(u.x),w4.x,acc); acc = fmaf(bf2f(u.y),w4.y,acc);
    acc = fmaf(bf2f(u.z),w4.z,acc); acc = fmaf(bf2f(u.w),w4.w,acc);
  }
  em[(size_t)word*T_ + t] = acc;
}

// ---------- K5a: gold-path score ----------
__global__ __launch_bounds__(256) void score_kernel(const int* __restrict__ tags,
    const float* __restrict__ em, const float* __restrict__ start,
    const float* __restrict__ end_, const float* __restrict__ trans,
    float* __restrict__ score){
  int b = blockIdx.x;
  int tid = threadIdx.x;
  const int* tg = tags + b*S_;
  const float* eb = em + (size_t)b*S_*T_;
  float s = 0.0f;
  for (int t = tid; t < S_; t += 256){
    int cur = tg[t];
    s += eb[(size_t)t*T_ + cur];
    if (t > 0) s += trans[tg[t-1]*T_ + cur];
  }
  if (tid == 0) s += start[tg[0]] + end_[tg[S_-1]];
  __shared__ float red[256];
  red[tid] = s; __syncthreads();
  for (int off=128; off; off>>=1){
    if (tid < off) red[tid] += red[tid+off];
    __syncthreads();
  }
  if (tid == 0) score[b] = red[0];
}

// ---------- K5b: CRF forward recursion (single wave: no barriers) ----------
__global__ __launch_bounds__(64) void crf_alpha_kernel(const float* __restrict__ em,
    const float* __restrict__ start, const float* __restrict__ end_,
    const float* __restrict__ trans, float* __restrict__ logZ){
  int b = blockIdx.x;
  int j = threadIdx.x;          // lane j owns tag j (j<17); block = ONE wave
  __shared__ float al[T_];
  const float* eb = em + (size_t)b*S_*T_;
  float tcol[T_];
  if (j < T_){
    #pragma unroll
    for (int i=0;i<T_;++i) tcol[i] = trans[i*T_ + j];
    al[j] = start[j] + eb[j];
  }
  float e_cur = (j < T_) ? eb[T_ + j] : 0.0f;
  for (int s=1;s<S_;++s){
    float e_nxt = (j < T_ && s+1 < S_) ? eb[(size_t)(s+1)*T_ + j] : 0.0f;
    if (j < T_){
      float av[T_];
      float m = -1e30f;
      #pragma unroll
      for (int i=0;i<T_;++i){ av[i] = al[i] + tcol[i]; m = fmaxf(m, av[i]); }
      float sum = 0.0f;
      #pragma unroll
      for (int i=0;i<T_;++i) sum += __expf(av[i]-m);
      float nv = m + __logf(sum) + e_cur;
      al[j] = nv;                 // same-wave LDS ops are program-ordered
    }
    e_cur = e_nxt;
  }
  if (j == 0){
    float m = -1e30f;
    float v[T_];
    #pragma unroll
    for (int i=0;i<T_;++i){ v[i] = al[i] + end_[i]; m = fmaxf(m, v[i]); }
    float sum = 0.0f;
    #pragma unroll
    for (int i=0;i<T_;++i) sum += __expf(v[i]-m);
    logZ[b] = m + __logf(sum);
  }
}

// ---------- K6: final scalar ----------
__global__ __launch_bounds__(128) void final_kernel(const float* __restrict__ logZ,
    const float* __restrict__ score, float* __restrict__ out){
  int tid = threadIdx.x;
  float v = logZ[tid] - score[tid];
  __shared__ float red[128];
  red[tid] = v; __syncthreads();
  for (int off=64; off; off>>=1){
    if (tid < off) red[tid] += red[tid+off];
    __syncthreads();
  }
  if (tid == 0) out[0] = red[0];
}

extern "C" void kernel_launch(void* const* d_in, const int* in_sizes, int n_in,
                              void* d_out, int out_size, void* d_ws, size_t ws_size,
                              hipStream_t stream) {
  const int*   x       = (const int*)  d_in[0];
  const int*   char_x  = (const int*)  d_in[1];
  const int*   tags    = (const int*)  d_in[2];
  // d_in[3] = mask: constitutively all-ones -> unused
  const float* wemb    = (const float*)d_in[4];
  const float* cemb    = (const float*)d_in[5];
  const float* c2W     = (const float*)d_in[6];
  const float* c2b     = (const float*)d_in[7];
  const float* c3W     = (const float*)d_in[8];
  const float* c3b     = (const float*)d_in[9];
  const float* c4W     = (const float*)d_in[10];
  const float* c4b     = (const float*)d_in[11];
  const float* Wih_f   = (const float*)d_in[12];
  const float* Whh_f   = (const float*)d_in[13];
  const float* b_f     = (const float*)d_in[14];
  const float* Wih_b   = (const float*)d_in[15];
  const float* Whh_b   = (const float*)d_in[16];
  const float* b_b     = (const float*)d_in[17];
  const float* h2tW    = (const float*)d_in[18];
  const float* h2tb    = (const float*)d_in[19];
  const float* crf_s   = (const float*)d_in[20];
  const float* crf_e   = (const float*)d_in[21];
  const float* crf_t   = (const float*)d_in[22];
  float* out = (float*)d_out;

  // ---- workspace layout (bytes) — R9 minus wpk2 ----
  // pre   (bf16 [2][128][512][512]) 134,217,728 @ 0
  // feats (bf16 [65536][192])        25,165,824 @ 134,217,728  (dead after pre_gemm)
  // wpk   (bf16 [1024][192])            393,216 @ 159,383,552  (dead after pre_gemm)
  // hs    (bf16 [2][65536][128])     33,554,432 @ 134,217,728  (overlaps dead feats+wpk)
  // em    (f32  [65536][17])          4,456,448 @ 0            (overlaps dead pre)
  // score / logZ                      @ 167,772,160 / 167,772,672
  const size_t NEEDED = 167773184ULL;
  if (ws_size < NEEDED) return;   // clean numeric failure instead of GPU fault
  char* wsb = (char*)d_ws;
  bf16*  pre   = (bf16*)(wsb);
  bf16*  feats = (bf16*)(wsb + 134217728);
  bf16*  wpk   = (bf16*)(wsb + 159383552);
  bf16*  hs    = (bf16*)(wsb + 134217728);
  float* em    = (float*)(wsb);
  float* score = (float*)(wsb + 167772160);
  float* logZ  = (float*)(wsb + 167772672);

  zero_pad_kernel<<<4352, 256, 0, stream>>>(feats);
  word_emb_kernel<<<32768, 256, 0, stream>>>(x, wemb, feats);
  char_conv_kernel<2><<<6400, 256, 0, stream>>>(char_x, cemb, c2W, c2b, feats, E_);
  char_conv_kernel<3><<<6400, 256, 0, stream>>>(char_x, cemb, c3W, c3b, feats, E_ + NF_);
  char_conv_kernel<4><<<6400, 256, 0, stream>>>(char_x, cemb, c4W, c4b, feats, E_ + 2*NF_);
  wpack_kernel<<<1024, 192, 0, stream>>>(Wih_f, Wih_b, wpk);
  pre_gemm_mfma<<<dim3(512, 8), 256, 0, stream>>>(feats, wpk, b_f, b_b, pre);
  lstm_valu_kernel<<<256, 512, 0, stream>>>(pre, Whh_f, Whh_b, hs);
  emis_kernel<<<4352, 256, 0, stream>>>(hs, h2tW, h2tb, em);
  score_kernel<<<128, 256, 0, stream>>>(tags, em, crf_s, crf_e, crf_t, score);
  crf_alpha_kernel<<<128, 64, 0, stream>>>(em, crf_s, crf_e, crf_t, logZ);
  final_kernel<<<1, 128, 0, stream>>>(logZ, score, out);
}

// Round 14
// 1616.935 us; speedup vs baseline: 1.1235x; 1.0003x over previous
//
#include <hip/hip_runtime.h>
#include <hip/hip_bf16.h>

#define B_ 128
#define S_ 512
#define C_ 16
#define E_ 100
#define CE_ 30
#define NF_ 25
#define H_ 128
#define T_ 17
#define LSTM_IN_ 175
#define KP_ 192        // feats K padded to multiple of 32 for MFMA
#define G4_ 512        // 4*H

typedef __hip_bfloat16 bf16;
typedef short bf16x8 __attribute__((ext_vector_type(8)));
typedef float f32x4 __attribute__((ext_vector_type(4)));

// ---------- helpers ----------
__device__ __forceinline__ float bf2f(unsigned short u){
  union { unsigned int i; float f; } v; v.i = ((unsigned int)u) << 16; return v.f;
}
__device__ __forceinline__ float sigm_f(float x){
  float e = __expf(-x);
  return __builtin_amdgcn_rcpf(1.0f + e);
}
__device__ __forceinline__ float tanh_f(float x){
  x = fminf(15.0f, fmaxf(-15.0f, x));
  float e = __expf(-2.0f*x);
  return (1.0f - e) * __builtin_amdgcn_rcpf(1.0f + e);
}
__device__ __forceinline__ short bf16bits(float f){
  bf16 b = __float2bfloat16(f);
  return *(short*)&b;
}

// ---------- K-1: zero the K-pad columns of feats ----------
__global__ __launch_bounds__(256) void zero_pad_kernel(bf16* __restrict__ feats){
  int task = blockIdx.x*256 + threadIdx.x;      // 65536*17 = 1,114,112 exact
  int word = task / 17;
  int col = LSTM_IN_ + (task - word*17);        // 175..191
  feats[(size_t)word*KP_ + col] = __float2bfloat16(0.0f);
}

// ---------- K0: word embedding gather -> feats[:, 0:100] ----------
__global__ __launch_bounds__(256) void word_emb_kernel(const int* __restrict__ x,
    const float* __restrict__ wemb, bf16* __restrict__ feats){
  int word = blockIdx.x*2 + (threadIdx.x>>7);
  int e = threadIdx.x & 127;
  if (e < E_) feats[(size_t)word*KP_ + e] = __float2bfloat16(wemb[(size_t)x[word]*E_ + e]);
}

// ---------- K1: char conv (f32, stride-192 out) ----------
template<int KW>
__global__ __launch_bounds__(256) void char_conv_kernel(const int* __restrict__ char_x,
    const float* __restrict__ cemb, const float* __restrict__ W,
    const float* __restrict__ bias, bf16* __restrict__ feats, int out_off){
  int task = blockIdx.x*256 + threadIdx.x;     // 65536*25 tasks
  int word = task / NF_;
  int fi = task - word*NF_;
  const int* cx = char_x + word*C_;
  float w[KW*CE_];
  #pragma unroll
  for (int i=0;i<KW*CE_;++i) w[i] = W[fi*CE_*KW + i];   // [fi][e][dx]
  const int NP = C_ - KW + 1;
  float acc[C_ - KW + 1];
  #pragma unroll
  for (int p=0;p<NP;++p) acc[p] = 0.0f;
  #pragma unroll
  for (int c=0;c<C_;++c){
    int ci = cx[c];
    const float* ce = cemb + ci*CE_;
    #pragma unroll
    for (int e=0;e<CE_;++e){
      float v = ce[e];
      #pragma unroll
      for (int dx=0;dx<KW;++dx){
        int p = c - dx;
        if (p >= 0 && p < NP) acc[p] = fmaf(v, w[e*KW+dx], acc[p]);
      }
    }
  }
  float m = acc[0];
  #pragma unroll
  for (int p=1;p<NP;++p) m = fmaxf(m, acc[p]);
  feats[(size_t)word*KP_ + out_off + fi] = __float2bfloat16(fmaxf(0.0f, m + bias[fi]));
}

// ---------- W_ih f32 [512][175] (x2 dirs) -> bf16 [1024][192] zero-padded ----------
__global__ __launch_bounds__(192) void wpack_kernel(const float* __restrict__ Wf,
    const float* __restrict__ Wb, bf16* __restrict__ wpk){
  int g = blockIdx.x;            // 0..1023
  int k = threadIdx.x;           // 0..191
  float v = 0.0f;
  if (k < LSTM_IN_) v = (g < 512) ? Wf[g*LSTM_IN_ + k] : Wb[(g-512)*LSTM_IN_ + k];
  wpk[(size_t)g*KP_ + k] = __float2bfloat16(v);
}

// ---------- K2: pre = feats @ W_ih^T + b  (MFMA bf16, global_load_lds, dbuf) ----------
__global__ __launch_bounds__(256, 3) void pre_gemm_mfma(const bf16* __restrict__ feats,
    const bf16* __restrict__ wpk, const float* __restrict__ bf_,
    const float* __restrict__ bb_, bf16* __restrict__ pre){
  __shared__ __align__(16) short lds[16384];   // 32KB: 2 x (A 4096 + B 4096); reused as C-stage
  int br = blockIdx.x;           // 0..511
  int bc = blockIdx.y;           // 0..7
  int dir = bc >> 2;
  int g0 = (bc & 3) * 128;
  const float* bias = dir ? bb_ : bf_;
  int tid = threadIdx.x;
  int wave = tid >> 6, lane = tid & 63;
  int wr = wave >> 1, wc = wave & 1;
  int lrow = lane & 15, lkb = lane >> 4;
  const bf16* Arow = feats + (size_t)br*128*KP_;
  const bf16* Brow = wpk + (size_t)(dir*512 + g0)*KP_;

  auto stage = [&](int bufbase, int k0){
    int s0 = wave*2, s1 = s0 + 1;
    __builtin_amdgcn_global_load_lds(
        (const __attribute__((address_space(1))) void*)(Arow + (size_t)(s0*16 + lrow)*KP_ + k0 + lkb*8),
        (__attribute__((address_space(3))) void*)&lds[bufbase + s0*512], 16, 0, 0);
    __builtin_amdgcn_global_load_lds(
        (const __attribute__((address_space(1))) void*)(Arow + (size_t)(s1*16 + lrow)*KP_ + k0 + lkb*8),
        (__attribute__((address_space(3))) void*)&lds[bufbase + s1*512], 16, 0, 0);
    __builtin_amdgcn_global_load_lds(
        (const __attribute__((address_space(1))) void*)(Brow + (size_t)(s0*16 + lrow)*KP_ + k0 + lkb*8),
        (__attribute__((address_space(3))) void*)&lds[bufbase + 4096 + s0*512], 16, 0, 0);
    __builtin_amdgcn_global_load_lds(
        (const __attribute__((address_space(1))) void*)(Brow + (size_t)(s1*16 + lrow)*KP_ + k0 + lkb*8),
        (__attribute__((address_space(3))) void*)&lds[bufbase + 4096 + s1*512], 16, 0, 0);
  };

  f32x4 acc[4][4];
  #pragma unroll
  for (int i=0;i<4;++i)
    #pragma unroll
    for (int j=0;j<4;++j) acc[i][j] = (f32x4){0.f,0.f,0.f,0.f};

  stage(0, 0);
  __syncthreads();
  int cur = 0;
  for (int t = 0; t < 6; ++t){
    if (t < 5) stage((cur^1)*8192, (t+1)*32);
    const short* A  = &lds[cur*8192];
    const short* Bv = &lds[cur*8192 + 4096];
    bf16x8 af[4], bfr[4];
    #pragma unroll
    for (int i=0;i<4;++i) af[i]  = *(const bf16x8*)&A[(wr*4+i)*512 + lane*8];
    #pragma unroll
    for (int j=0;j<4;++j) bfr[j] = *(const bf16x8*)&Bv[(wc*4+j)*512 + lane*8];
    #pragma unroll
    for (int i=0;i<4;++i)
      #pragma unroll
      for (int j=0;j<4;++j)
        acc[i][j] = __builtin_amdgcn_mfma_f32_16x16x32_bf16(af[i], bfr[j], acc[i][j], 0, 0, 0);
    __syncthreads();
    cur ^= 1;
  }

  // epilogue: swizzled C-stage in LDS, then coalesced 16B global stores
  int col_l = lane & 15;
  int row_l = (lane >> 4) * 4;
  float bias_v[4];
  #pragma unroll
  for (int j=0;j<4;++j) bias_v[j] = bias[g0 + wc*64 + j*16 + col_l];
  #pragma unroll
  for (int i=0;i<4;++i){
    #pragma unroll
    for (int q=0;q<4;++q){
      int r = wr*64 + i*16 + row_l + q;
      #pragma unroll
      for (int j=0;j<4;++j){
        int cbyte = (wc*64 + j*16 + col_l) * 2;
        int addr = r*256 + (cbyte ^ ((r & 7) << 4));
        *(short*)((char*)lds + addr) = bf16bits(acc[i][j][q] + bias_v[j]);
      }
    }
  }
  __syncthreads();
  int r = tid >> 1, half = tid & 1;
  int word = br*128 + r;
  int bidx = word >> 9, sidx = word & 511;
  bf16* dst = pre + ((size_t)(dir*B_ + bidx)*S_ + sidx)*G4_ + g0 + half*64;
  #pragma unroll
  for (int k=0;k<8;++k){
    int boff = (half*128 + k*16) ^ ((r & 7) << 4);
    int4 v = *(const int4*)((const char*)lds + r*256 + boff);
    *(int4*)((char*)dst + k*16) = v;
  }
}

// ---------- K3: LSTM recurrence, VALU, all 256 CUs; Whh resident via waves_per_eu cap ----------
// 1 block per (dir, batch). 512 threads; thread g owns gate g. 2 raw barriers/step.
// amdgpu_waves_per_eu(2,2): allocator targets exactly 2 waves/EU -> 256-VGPR budget,
// no occupancy credit above 2 -> keeps the 128-VGPR weight array resident.
__global__ __launch_bounds__(512)
__attribute__((amdgpu_waves_per_eu(2, 2)))
void lstm_valu_kernel(
    const bf16* __restrict__ pre, const float* __restrict__ Whh_f,
    const float* __restrict__ Whh_b, bf16* __restrict__ hs){
  int blk = blockIdx.x;          // 0..255
  int dir = blk & 1;
  int b = blk >> 1;
  int g = threadIdx.x;           // 0..511
  const float* Whh = dir ? Whh_b : Whh_f;
  f32x4 w4[32];                  // Whh row, 128 VGPRs, pinned resident (ext-vector: asm-legal)
  #pragma unroll
  for (int i=0;i<32;++i){
    w4[i] = *(const f32x4*)(Whh + g*H_ + 4*i);
    asm volatile("" : "+v"(w4[i]));
  }
  __shared__ __align__(16) float h_lds[H_];
  __shared__ float gates[G4_];
  if (g < H_) h_lds[g] = 0.0f;
  __syncthreads();
  const bf16* preB = pre + ((size_t)dir*B_ + b)*S_*G4_;
  bf16* hsB = hs + ((size_t)dir*B_ + b)*S_*H_;
  float c = 0.0f;
  int sect = g >> 7;             // 0:i 1:f 2:g 3:o  (wave-uniform)
  unsigned short u0 = *(const unsigned short*)(preB + (size_t)(dir ? (S_-1) : 0)*G4_ + g);
  unsigned short u1 = *(const unsigned short*)(preB + (size_t)(dir ? (S_-2) : 1)*G4_ + g);
  for (int s=0;s<S_;++s){
    int idx = dir ? (S_-1-s) : s;
    float pr = bf2f(u0);
    u0 = u1;
    if (s+2 < S_){
      int idx2 = dir ? (S_-3-s) : (s+2);
      u1 = *(const unsigned short*)(preB + (size_t)idx2*G4_ + g);   // stays in flight
    }
    float a0=0.f, a1=0.f, a2=0.f, a3=0.f;      // 4 independent chains
    const f32x4* hp = (const f32x4*)h_lds;
    #pragma unroll
    for (int k=0;k<32;++k){
      f32x4 hk = hp[k];                         // LDS broadcast, 16B
      f32x4 wk = w4[k];
      a0 = fmaf(wk[0], hk[0], a0);
      a1 = fmaf(wk[1], hk[1], a1);
      a2 = fmaf(wk[2], hk[2], a2);
      a3 = fmaf(wk[3], hk[3], a3);
    }
    float acc = pr + ((a0+a1)+(a2+a3));
    float a = (sect == 2) ? tanh_f(acc) : sigm_f(acc);
    gates[g] = a;
    asm volatile("s_waitcnt lgkmcnt(0)" ::: "memory");   // gates-write landed (LDS only)
    __builtin_amdgcn_s_barrier();                        // B1: gates visible
    asm volatile("" ::: "memory");
    if (g < H_){                                         // wave-uniform (waves 0-1)
      float iv = gates[g];
      float fv = gates[g+128];
      float gv = gates[g+256];
      float ov = gates[g+384];
      c = fmaf(fv, c, iv*gv);
      float hn = ov * tanh_f(c);
      h_lds[g] = hn;
      hsB[(size_t)idx*H_ + g] = __float2bfloat16(hn);
    }
    asm volatile("s_waitcnt lgkmcnt(0)" ::: "memory");   // h-write landed (LDS only)
    __builtin_amdgcn_s_barrier();                        // B2: new h visible
    asm volatile("" ::: "memory");
  }
}

// ---------- K4: emissions ----------
__global__ __launch_bounds__(256) void emis_kernel(const bf16* __restrict__ hs,
    const float* __restrict__ W, const float* __restrict__ bias, float* __restrict__ em){
  int task = blockIdx.x*256 + threadIdx.x;     // 65536*17 tasks
  int word = task / T_;
  int t = task - word*T_;
  const ushort4* hf = (const ushort4*)(hs + (size_t)word*H_);
  const ushort4* hb = (const ushort4*)(hs + (size_t)(B_*S_ + word)*H_);
  const float* w0 = W + t*2*H_;
  float acc = bias[t];
  #pragma unroll
  for (int j4=0;j4<32;++j4){
    ushort4 u = hf[j4];
    float4 w4 = *(const float4*)&w0[j4*4];
    acc = fmaf(bf2f(u.x),w4.x,acc); acc = fmaf(bf2f(u.y),w4.y,acc);
    acc = fmaf(bf2f(u.z),w4.z,acc); acc = fmaf(bf2f(u.w),w4.w,acc);
  }
  #pragma unroll
  for (int j4=0;j4<32;++j4){
    ushort4 u = hb[j4];
    float4 w4 = *(const float4*)&w0[H_ + j4*4];
    acc = fmaf(bf2f(u.x),w4.x,acc); acc = fmaf(bf2f(u.y),w4.y,acc);
    acc = fmaf(bf2f(u.z),w4.z,acc); acc = fmaf(bf2f(u.w),w4.w,acc);
  }
  em[(size_t)word*T_ + t] = acc;
}

// ---------- K5a: gold-path score ----------
__global__ __launch_bounds__(256) void score_kernel(const int* __restrict__ tags,
    const float* __restrict__ em, const float* __restrict__ start,
    const float* __restrict__ end_, const float* __restrict__ trans,
    float* __restrict__ score){
  int b = blockIdx.x;
  int tid = threadIdx.x;
  const int* tg = tags + b*S_;
  const float* eb = em + (size_t)b*S_*T_;
  float s = 0.0f;
  for (int t = tid; t < S_; t += 256){
    int cur = tg[t];
    s += eb[(size_t)t*T_ + cur];
    if (t > 0) s += trans[tg[t-1]*T_ + cur];
  }
  if (tid == 0) s += start[tg[0]] + end_[tg[S_-1]];
  __shared__ float red[256];
  red[tid] = s; __syncthreads();
  for (int off=128; off; off>>=1){
    if (tid < off) red[tid] += red[tid+off];
    __syncthreads();
  }
  if (tid == 0) score[b] = red[0];
}

// ---------- K5b: CRF forward recursion (single wave: no barriers) ----------
__global__ __launch_bounds__(64) void crf_alpha_kernel(const float* __restrict__ em,
    const float* __restrict__ start, const float* __restrict__ end_,
    const float* __restrict__ trans, float* __restrict__ logZ){
  int b = blockIdx.x;
  int j = threadIdx.x;          // lane j owns tag j (j<17); block = ONE wave
  __shared__ float al[T_];
  const float* eb = em + (size_t)b*S_*T_;
  float tcol[T_];
  if (j < T_){
    #pragma unroll
    for (int i=0;i<T_;++i) tcol[i] = trans[i*T_ + j];
    al[j] = start[j] + eb[j];
  }
  float e_cur = (j < T_) ? eb[T_ + j] : 0.0f;
  for (int s=1;s<S_;++s){
    float e_nxt = (j < T_ && s+1 < S_) ? eb[(size_t)(s+1)*T_ + j] : 0.0f;
    if (j < T_){
      float av[T_];
      float m = -1e30f;
      #pragma unroll
      for (int i=0;i<T_;++i){ av[i] = al[i] + tcol[i]; m = fmaxf(m, av[i]); }
      float sum = 0.0f;
      #pragma unroll
      for (int i=0;i<T_;++i) sum += __expf(av[i]-m);
      float nv = m + __logf(sum) + e_cur;
      al[j] = nv;                 // same-wave LDS ops are program-ordered
    }
    e_cur = e_nxt;
  }
  if (j == 0){
    float m = -1e30f;
    float v[T_];
    #pragma unroll
    for (int i=0;i<T_;++i){ v[i] = al[i] + end_[i]; m = fmaxf(m, v[i]); }
    float sum = 0.0f;
    #pragma unroll
    for (int i=0;i<T_;++i) sum += __expf(v[i]-m);
    logZ[b] = m + __logf(sum);
  }
}

// ---------- K6: final scalar ----------
__global__ __launch_bounds__(128) void final_kernel(const float* __restrict__ logZ,
    const float* __restrict__ score, float* __restrict__ out){
  int tid = threadIdx.x;
  float v = logZ[tid] - score[tid];
  __shared__ float red[128];
  red[tid] = v; __syncthreads();
  for (int off=64; off; off>>=1){
    if (tid < off) red[tid] += red[tid+off];
    __syncthreads();
  }
  if (tid == 0) out[0] = red[0];
}

extern "C" void kernel_launch(void* const* d_in, const int* in_sizes, int n_in,
                              void* d_out, int out_size, void* d_ws, size_t ws_size,
                              hipStream_t stream) {
  const int*   x       = (const int*)  d_in[0];
  const int*   char_x  = (const int*)  d_in[1];
  const int*   tags    = (const int*)  d_in[2];
  // d_in[3] = mask: constitutively all-ones -> unused
  const float* wemb    = (const float*)d_in[4];
  const float* cemb    = (const float*)d_in[5];
  const float* c2W     = (const float*)d_in[6];
  const float* c2b     = (const float*)d_in[7];
  const float* c3W     = (const float*)d_in[8];
  const float* c3b     = (const float*)d_in[9];
  const float* c4W     = (const float*)d_in[10];
  const float* c4b     = (const float*)d_in[11];
  const float* Wih_f   = (const float*)d_in[12];
  const float* Whh_f   = (const float*)d_in[13];
  const float* b_f     = (const float*)d_in[14];
  const float* Wih_b   = (const float*)d_in[15];
  const float* Whh_b   = (const float*)d_in[16];
  const float* b_b     = (const float*)d_in[17];
  const float* h2tW    = (const float*)d_in[18];
  const float* h2tb    = (const float*)d_in[19];
  const float* crf_s   = (const float*)d_in[20];
  const float* crf_e   = (const float*)d_in[21];
  const float* crf_t   = (const float*)d_in[22];
  float* out = (float*)d_out;

  // ---- workspace layout (bytes) — R9 minus wpk2 ----
  // pre   (bf16 [2][128][512][512]) 134,217,728 @ 0
  // feats (bf16 [65536][192])        25,165,824 @ 134,217,728  (dead after pre_gemm)
  // wpk   (bf16 [1024][192])            393,216 @ 159,383,552  (dead after pre_gemm)
  // hs    (bf16 [2][65536][128])     33,554,432 @ 134,217,728  (overlaps dead feats+wpk)
  // em    (f32  [65536][17])          4,456,448 @ 0            (overlaps dead pre)
  // score / logZ                      @ 167,772,160 / 167,772,672
  const size_t NEEDED = 167773184ULL;
  if (ws_size < NEEDED) return;   // clean numeric failure instead of GPU fault
  char* wsb = (char*)d_ws;
  bf16*  pre   = (bf16*)(wsb);
  bf16*  feats = (bf16*)(wsb + 134217728);
  bf16*  wpk   = (bf16*)(wsb + 159383552);
  bf16*  hs    = (bf16*)(wsb + 134217728);
  float* em    = (float*)(wsb);
  float* score = (float*)(wsb + 167772160);
  float* logZ  = (float*)(wsb + 167772672);

  zero_pad_kernel<<<4352, 256, 0, stream>>>(feats);
  word_emb_kernel<<<32768, 256, 0, stream>>>(x, wemb, feats);
  char_conv_kernel<2><<<6400, 256, 0, stream>>>(char_x, cemb, c2W, c2b, feats, E_);
  char_conv_kernel<3><<<6400, 256, 0, stream>>>(char_x, cemb, c3W, c3b, feats, E_ + NF_);
  char_conv_kernel<4><<<6400, 256, 0, stream>>>(char_x, cemb, c4W, c4b, feats, E_ + 2*NF_);
  wpack_kernel<<<1024, 192, 0, stream>>>(Wih_f, Wih_b, wpk);
  pre_gemm_mfma<<<dim3(512, 8), 256, 0, stream>>>(feats, wpk, b_f, b_b, pre);
  lstm_valu_kernel<<<256, 512, 0, stream>>>(pre, Whh_f, Whh_b, hs);
  emis_kernel<<<4352, 256, 0, stream>>>(hs, h2tW, h2tb, em);
  score_kernel<<<128, 256, 0, stream>>>(tags, em, crf_s, crf_e, crf_t, score);
  crf_alpha_kernel<<<128, 64, 0, stream>>>(em, crf_s, crf_e, crf_t, logZ);
  final_kernel<<<1, 128, 0, stream>>>(logZ, score, out);
}

// Round 15
// 1614.127 us; speedup vs baseline: 1.1255x; 1.0017x over previous
//
#include <hip/hip_runtime.h>
#include <hip/hip_bf16.h>

#define B_ 128
#define S_ 512
#define C_ 16
#define E_ 100
#define CE_ 30
#define NF_ 25
#define H_ 128
#define T_ 17
#define LSTM_IN_ 175
#define KP_ 192        // feats K padded to multiple of 32 for MFMA
#define G4_ 512        // 4*H

typedef __hip_bfloat16 bf16;
typedef short bf16x8 __attribute__((ext_vector_type(8)));
typedef float f32x4 __attribute__((ext_vector_type(4)));

// ---------- helpers ----------
__device__ __forceinline__ float bf2f(unsigned short u){
  union { unsigned int i; float f; } v; v.i = ((unsigned int)u) << 16; return v.f;
}
__device__ __forceinline__ float sigm_f(float x){
  float e = __expf(-x);
  return __builtin_amdgcn_rcpf(1.0f + e);
}
__device__ __forceinline__ float tanh_f(float x){
  x = fminf(15.0f, fmaxf(-15.0f, x));
  float e = __expf(-2.0f*x);
  return (1.0f - e) * __builtin_amdgcn_rcpf(1.0f + e);
}
__device__ __forceinline__ short bf16bits(float f){
  bf16 b = __float2bfloat16(f);
  return *(short*)&b;
}

// ---------- K-1: zero the K-pad columns of feats ----------
__global__ __launch_bounds__(256) void zero_pad_kernel(bf16* __restrict__ feats){
  int task = blockIdx.x*256 + threadIdx.x;      // 65536*17 = 1,114,112 exact
  int word = task / 17;
  int col = LSTM_IN_ + (task - word*17);        // 175..191
  feats[(size_t)word*KP_ + col] = __float2bfloat16(0.0f);
}

// ---------- K0: word embedding gather -> feats[:, 0:100] ----------
__global__ __launch_bounds__(256) void word_emb_kernel(const int* __restrict__ x,
    const float* __restrict__ wemb, bf16* __restrict__ feats){
  int word = blockIdx.x*2 + (threadIdx.x>>7);
  int e = threadIdx.x & 127;
  if (e < E_) feats[(size_t)word*KP_ + e] = __float2bfloat16(wemb[(size_t)x[word]*E_ + e]);
}

// ---------- K1: char conv (f32, stride-192 out) ----------
template<int KW>
__global__ __launch_bounds__(256) void char_conv_kernel(const int* __restrict__ char_x,
    const float* __restrict__ cemb, const float* __restrict__ W,
    const float* __restrict__ bias, bf16* __restrict__ feats, int out_off){
  int task = blockIdx.x*256 + threadIdx.x;     // 65536*25 tasks
  int word = task / NF_;
  int fi = task - word*NF_;
  const int* cx = char_x + word*C_;
  float w[KW*CE_];
  #pragma unroll
  for (int i=0;i<KW*CE_;++i) w[i] = W[fi*CE_*KW + i];   // [fi][e][dx]
  const int NP = C_ - KW + 1;
  float acc[C_ - KW + 1];
  #pragma unroll
  for (int p=0;p<NP;++p) acc[p] = 0.0f;
  #pragma unroll
  for (int c=0;c<C_;++c){
    int ci = cx[c];
    const float* ce = cemb + ci*CE_;
    #pragma unroll
    for (int e=0;e<CE_;++e){
      float v = ce[e];
      #pragma unroll
      for (int dx=0;dx<KW;++dx){
        int p = c - dx;
        if (p >= 0 && p < NP) acc[p] = fmaf(v, w[e*KW+dx], acc[p]);
      }
    }
  }
  float m = acc[0];
  #pragma unroll
  for (int p=1;p<NP;++p) m = fmaxf(m, acc[p]);
  feats[(size_t)word*KP_ + out_off + fi] = __float2bfloat16(fmaxf(0.0f, m + bias[fi]));
}

// ---------- W_ih f32 [512][175] (x2 dirs) -> bf16 [1024][192] zero-padded ----------
__global__ __launch_bounds__(192) void wpack_kernel(const float* __restrict__ Wf,
    const float* __restrict__ Wb, bf16* __restrict__ wpk){
  int g = blockIdx.x;            // 0..1023
  int k = threadIdx.x;           // 0..191
  float v = 0.0f;
  if (k < LSTM_IN_) v = (g < 512) ? Wf[g*LSTM_IN_ + k] : Wb[(g-512)*LSTM_IN_ + k];
  wpk[(size_t)g*KP_ + k] = __float2bfloat16(v);
}

// ---------- K2: pre = feats @ W_ih^T + b  (MFMA bf16, global_load_lds, dbuf) ----------
__global__ __launch_bounds__(256, 3) void pre_gemm_mfma(const bf16* __restrict__ feats,
    const bf16* __restrict__ wpk, const float* __restrict__ bf_,
    const float* __restrict__ bb_, bf16* __restrict__ pre){
  __shared__ __align__(16) short lds[16384];   // 32KB: 2 x (A 4096 + B 4096); reused as C-stage
  int br = blockIdx.x;           // 0..511
  int bc = blockIdx.y;           // 0..7
  int dir = bc >> 2;
  int g0 = (bc & 3) * 128;
  const float* bias = dir ? bb_ : bf_;
  int tid = threadIdx.x;
  int wave = tid >> 6, lane = tid & 63;
  int wr = wave >> 1, wc = wave & 1;
  int lrow = lane & 15, lkb = lane >> 4;
  const bf16* Arow = feats + (size_t)br*128*KP_;
  const bf16* Brow = wpk + (size_t)(dir*512 + g0)*KP_;

  auto stage = [&](int bufbase, int k0){
    int s0 = wave*2, s1 = s0 + 1;
    __builtin_amdgcn_global_load_lds(
        (const __attribute__((address_space(1))) void*)(Arow + (size_t)(s0*16 + lrow)*KP_ + k0 + lkb*8),
        (__attribute__((address_space(3))) void*)&lds[bufbase + s0*512], 16, 0, 0);
    __builtin_amdgcn_global_load_lds(
        (const __attribute__((address_space(1))) void*)(Arow + (size_t)(s1*16 + lrow)*KP_ + k0 + lkb*8),
        (__attribute__((address_space(3))) void*)&lds[bufbase + s1*512], 16, 0, 0);
    __builtin_amdgcn_global_load_lds(
        (const __attribute__((address_space(1))) void*)(Brow + (size_t)(s0*16 + lrow)*KP_ + k0 + lkb*8),
        (__attribute__((address_space(3))) void*)&lds[bufbase + 4096 + s0*512], 16, 0, 0);
    __builtin_amdgcn_global_load_lds(
        (const __attribute__((address_space(1))) void*)(Brow + (size_t)(s1*16 + lrow)*KP_ + k0 + lkb*8),
        (__attribute__((address_space(3))) void*)&lds[bufbase + 4096 + s1*512], 16, 0, 0);
  };

  f32x4 acc[4][4];
  #pragma unroll
  for (int i=0;i<4;++i)
    #pragma unroll
    for (int j=0;j<4;++j) acc[i][j] = (f32x4){0.f,0.f,0.f,0.f};

  stage(0, 0);
  __syncthreads();
  int cur = 0;
  for (int t = 0; t < 6; ++t){
    if (t < 5) stage((cur^1)*8192, (t+1)*32);
    const short* A  = &lds[cur*8192];
    const short* Bv = &lds[cur*8192 + 4096];
    bf16x8 af[4], bfr[4];
    #pragma unroll
    for (int i=0;i<4;++i) af[i]  = *(const bf16x8*)&A[(wr*4+i)*512 + lane*8];
    #pragma unroll
    for (int j=0;j<4;++j) bfr[j] = *(const bf16x8*)&Bv[(wc*4+j)*512 + lane*8];
    #pragma unroll
    for (int i=0;i<4;++i)
      #pragma unroll
      for (int j=0;j<4;++j)
        acc[i][j] = __builtin_amdgcn_mfma_f32_16x16x32_bf16(af[i], bfr[j], acc[i][j], 0, 0, 0);
    __syncthreads();
    cur ^= 1;
  }

  // epilogue: swizzled C-stage in LDS, then coalesced 16B global stores
  int col_l = lane & 15;
  int row_l = (lane >> 4) * 4;
  float bias_v[4];
  #pragma unroll
  for (int j=0;j<4;++j) bias_v[j] = bias[g0 + wc*64 + j*16 + col_l];
  #pragma unroll
  for (int i=0;i<4;++i){
    #pragma unroll
    for (int q=0;q<4;++q){
      int r = wr*64 + i*16 + row_l + q;
      #pragma unroll
      for (int j=0;j<4;++j){
        int cbyte = (wc*64 + j*16 + col_l) * 2;
        int addr = r*256 + (cbyte ^ ((r & 7) << 4));
        *(short*)((char*)lds + addr) = bf16bits(acc[i][j][q] + bias_v[j]);
      }
    }
  }
  __syncthreads();
  int r = tid >> 1, half = tid & 1;
  int word = br*128 + r;
  int bidx = word >> 9, sidx = word & 511;
  bf16* dst = pre + ((size_t)(dir*B_ + bidx)*S_ + sidx)*G4_ + g0 + half*64;
  #pragma unroll
  for (int k=0;k<8;++k){
    int boff = (half*128 + k*16) ^ ((r & 7) << 4);
    int4 v = *(const int4*)((const char*)lds + r*256 + boff);
    *(int4*)((char*)dst + k*16) = v;
  }
}

// ---------- K3: LSTM recurrence, VALU; LDS pad forces 1 block/CU ----------
// 1 block per (dir, batch) = 256 blocks = 256 CUs. 512 threads; thread g owns gate g.
// The 84KB dummy LDS allocation (a) prevents 2-3 blocks packing onto one CU
// (small-grid starvation) and (b) caps allocator occupancy target at 2 waves/SIMD,
// giving a 256-VGPR budget so w4[32] (128 VGPRs) stays resident.
__global__ __launch_bounds__(512) void lstm_valu_kernel(
    const bf16* __restrict__ pre, const float* __restrict__ Whh_f,
    const float* __restrict__ Whh_b, bf16* __restrict__ hs){
  __shared__ float lds_pad[21504];             // 86,016 B -> 1 block/CU
  int blk = blockIdx.x;          // 0..255
  int dir = blk & 1;
  int b = blk >> 1;
  int g = threadIdx.x;           // 0..511
  if (blk == 0x7fffffff) lds_pad[g] = 0.0f;    // opaque guard: keeps pad allocated
  const float* Whh = dir ? Whh_b : Whh_f;
  f32x4 w4[32];                  // Whh row, 128 VGPRs
  #pragma unroll
  for (int i=0;i<32;++i) w4[i] = *(const f32x4*)(Whh + g*H_ + 4*i);
  __shared__ __align__(16) float h_lds[H_];
  __shared__ float gates[G4_];
  if (g < H_) h_lds[g] = 0.0f;
  __syncthreads();
  const bf16* preB = pre + ((size_t)dir*B_ + b)*S_*G4_;
  bf16* hsB = hs + ((size_t)dir*B_ + b)*S_*H_;
  float c = 0.0f;
  int sect = g >> 7;             // 0:i 1:f 2:g 3:o  (wave-uniform)
  unsigned short u0 = *(const unsigned short*)(preB + (size_t)(dir ? (S_-1) : 0)*G4_ + g);
  unsigned short u1 = *(const unsigned short*)(preB + (size_t)(dir ? (S_-2) : 1)*G4_ + g);
  for (int s=0;s<S_;++s){
    int idx = dir ? (S_-1-s) : s;
    float pr = bf2f(u0);
    u0 = u1;
    if (s+2 < S_){
      int idx2 = dir ? (S_-3-s) : (s+2);
      u1 = *(const unsigned short*)(preB + (size_t)idx2*G4_ + g);   // stays in flight
    }
    float a0=0.f, a1=0.f, a2=0.f, a3=0.f;      // 4 independent chains
    const f32x4* hp = (const f32x4*)h_lds;
    #pragma unroll
    for (int k=0;k<32;++k){
      f32x4 hk = hp[k];                         // LDS broadcast, 16B
      f32x4 wk = w4[k];
      a0 = fmaf(wk[0], hk[0], a0);
      a1 = fmaf(wk[1], hk[1], a1);
      a2 = fmaf(wk[2], hk[2], a2);
      a3 = fmaf(wk[3], hk[3], a3);
    }
    float acc = pr + ((a0+a1)+(a2+a3));
    float a = (sect == 2) ? tanh_f(acc) : sigm_f(acc);
    gates[g] = a;
    asm volatile("s_waitcnt lgkmcnt(0)" ::: "memory");   // gates-write landed (LDS only)
    __builtin_amdgcn_s_barrier();                        // B1: gates visible
    asm volatile("" ::: "memory");
    if (g < H_){                                         // wave-uniform (waves 0-1)
      float iv = gates[g];
      float fv = gates[g+128];
      float gv = gates[g+256];
      float ov = gates[g+384];
      c = fmaf(fv, c, iv*gv);
      float hn = ov * tanh_f(c);
      h_lds[g] = hn;
      hsB[(size_t)idx*H_ + g] = __float2bfloat16(hn);
    }
    asm volatile("s_waitcnt lgkmcnt(0)" ::: "memory");   // h-write landed (LDS only)
    __builtin_amdgcn_s_barrier();                        // B2: new h visible
    asm volatile("" ::: "memory");
  }
}

// ---------- K4: emissions ----------
__global__ __launch_bounds__(256) void emis_kernel(const bf16* __restrict__ hs,
    const float* __restrict__ W, const float* __restrict__ bias, float* __restrict__ em){
  int task = blockIdx.x*256 + threadIdx.x;     // 65536*17 tasks
  int word = task / T_;
  int t = task - word*T_;
  const ushort4* hf = (const ushort4*)(hs + (size_t)word*H_);
  const ushort4* hb = (const ushort4*)(hs + (size_t)(B_*S_ + word)*H_);
  const float* w0 = W + t*2*H_;
  float acc = bias[t];
  #pragma unroll
  for (int j4=0;j4<32;++j4){
    ushort4 u = hf[j4];
    float4 w4 = *(const float4*)&w0[j4*4];
    acc = fmaf(bf2f(u.x),w4.x,acc); acc = fmaf(bf2f(u.y),w4.y,acc);
    acc = fmaf(bf2f(u.z),w4.z,acc); acc = fmaf(bf2f(u.w),w4.w,acc);
  }
  #pragma unroll
  for (int j4=0;j4<32;++j4){
    ushort4 u = hb[j4];
    float4 w4 = *(const float4*)&w0[H_ + j4*4];
    acc = fmaf(bf2f(u.x),w4.x,acc); acc = fmaf(bf2f(u.y),w4.y,acc);
    acc = fmaf(bf2f(u.z),w4.z,acc); acc = fmaf(bf2f(u.w),w4.w,acc);
  }
  em[(size_t)word*T_ + t] = acc;
}

// ---------- K5a: gold-path score ----------
__global__ __launch_bounds__(256) void score_kernel(const int* __restrict__ tags,
    const float* __restrict__ em, const float* __restrict__ start,
    const float* __restrict__ end_, const float* __restrict__ trans,
    float* __restrict__ score){
  int b = blockIdx.x;
  int tid = threadIdx.x;
  const int* tg = tags + b*S_;
  const float* eb = em + (size_t)b*S_*T_;
  float s = 0.0f;
  for (int t = tid; t < S_; t += 256){
    int cur = tg[t];
    s += eb[(size_t)t*T_ + cur];
    if (t > 0) s += trans[tg[t-1]*T_ + cur];
  }
  if (tid == 0) s += start[tg[0]] + end_[tg[S_-1]];
  __shared__ float red[256];
  red[tid] = s; __syncthreads();
  for (int off=128; off; off>>=1){
    if (tid < off) red[tid] += red[tid+off];
    __syncthreads();
  }
  if (tid == 0) score[b] = red[0];
}

// ---------- K5b: CRF forward recursion (single wave: no barriers) ----------
__global__ __launch_bounds__(64) void crf_alpha_kernel(const float* __restrict__ em,
    const float* __restrict__ start, const float* __restrict__ end_,
    const float* __restrict__ trans, float* __restrict__ logZ){
  int b = blockIdx.x;
  int j = threadIdx.x;          // lane j owns tag j (j<17); block = ONE wave
  __shared__ float al[T_];
  const float* eb = em + (size_t)b*S_*T_;
  float tcol[T_];
  if (j < T_){
    #pragma unroll
    for (int i=0;i<T_;++i) tcol[i] = trans[i*T_ + j];
    al[j] = start[j] + eb[j];
  }
  float e_cur = (j < T_) ? eb[T_ + j] : 0.0f;
  for (int s=1;s<S_;++s){
    float e_nxt = (j < T_ && s+1 < S_) ? eb[(size_t)(s+1)*T_ + j] : 0.0f;
    if (j < T_){
      float av[T_];
      float m = -1e30f;
      #pragma unroll
      for (int i=0;i<T_;++i){ av[i] = al[i] + tcol[i]; m = fmaxf(m, av[i]); }
      float sum = 0.0f;
      #pragma unroll
      for (int i=0;i<T_;++i) sum += __expf(av[i]-m);
      float nv = m + __logf(sum) + e_cur;
      al[j] = nv;                 // same-wave LDS ops are program-ordered
    }
    e_cur = e_nxt;
  }
  if (j == 0){
    float m = -1e30f;
    float v[T_];
    #pragma unroll
    for (int i=0;i<T_;++i){ v[i] = al[i] + end_[i]; m = fmaxf(m, v[i]); }
    float sum = 0.0f;
    #pragma unroll
    for (int i=0;i<T_;++i) sum += __expf(v[i]-m);
    logZ[b] = m + __logf(sum);
  }
}

// ---------- K6: final scalar ----------
__global__ __launch_bounds__(128) void final_kernel(const float* __restrict__ logZ,
    const float* __restrict__ score, float* __restrict__ out){
  int tid = threadIdx.x;
  float v = logZ[tid] - score[tid];
  __shared__ float red[128];
  red[tid] = v; __syncthreads();
  for (int off=64; off; off>>=1){
    if (tid < off) red[tid] += red[tid+off];
    __syncthreads();
  }
  if (tid == 0) out[0] = red[0];
}

extern "C" void kernel_launch(void* const* d_in, const int* in_sizes, int n_in,
                              void* d_out, int out_size, void* d_ws, size_t ws_size,
                              hipStream_t stream) {
  const int*   x       = (const int*)  d_in[0];
  const int*   char_x  = (const int*)  d_in[1];
  const int*   tags    = (const int*)  d_in[2];
  // d_in[3] = mask: constitutively all-ones -> unused
  const float* wemb    = (const float*)d_in[4];
  const float* cemb    = (const float*)d_in[5];
  const float* c2W     = (const float*)d_in[6];
  const float* c2b     = (const float*)d_in[7];
  const float* c3W     = (const float*)d_in[8];
  const float* c3b     = (const float*)d_in[9];
  const float* c4W     = (const float*)d_in[10];
  const float* c4b     = (const float*)d_in[11];
  const float* Wih_f   = (const float*)d_in[12];
  const float* Whh_f   = (const float*)d_in[13];
  const float* b_f     = (const float*)d_in[14];
  const float* Wih_b   = (const float*)d_in[15];
  const float* Whh_b   = (const float*)d_in[16];
  const float* b_b     = (const float*)d_in[17];
  const float* h2tW    = (const float*)d_in[18];
  const float* h2tb    = (const float*)d_in[19];
  const float* crf_s   = (const float*)d_in[20];
  const float* crf_e   = (const float*)d_in[21];
  const float* crf_t   = (const float*)d_in[22];
  float* out = (float*)d_out;

  // ---- workspace layout (bytes) — R9 minus wpk2 ----
  // pre   (bf16 [2][128][512][512]) 134,217,728 @ 0
  // feats (bf16 [65536][192])        25,165,824 @ 134,217,728  (dead after pre_gemm)
  // wpk   (bf16 [1024][192])            393,216 @ 159,383,552  (dead after pre_gemm)
  // hs    (bf16 [2][65536][128])     33,554,432 @ 134,217,728  (overlaps dead feats+wpk)
  // em    (f32  [65536][17])          4,456,448 @ 0            (overlaps dead pre)
  // score / logZ                      @ 167,772,160 / 167,772,672
  const size_t NEEDED = 167773184ULL;
  if (ws_size < NEEDED) return;   // clean numeric failure instead of GPU fault
  char* wsb = (char*)d_ws;
  bf16*  pre   = (bf16*)(wsb);
  bf16*  feats = (bf16*)(wsb + 134217728);
  bf16*  wpk   = (bf16*)(wsb + 159383552);
  bf16*  hs    = (bf16*)(wsb + 134217728);
  float* em    = (float*)(wsb);
  float* score = (float*)(wsb + 167772160);
  float* logZ  = (float*)(wsb + 167772672);

  zero_pad_kernel<<<4352, 256, 0, stream>>>(feats);
  word_emb_kernel<<<32768, 256, 0, stream>>>(x, wemb, feats);
  char_conv_kernel<2><<<6400, 256, 0, stream>>>(char_x, cemb, c2W, c2b, feats, E_);
  char_conv_kernel<3><<<6400, 256, 0, stream>>>(char_x, cemb, c3W, c3b, feats, E_ + NF_);
  char_conv_kernel<4><<<6400, 256, 0, stream>>>(char_x, cemb, c4W, c4b, feats, E_ + 2*NF_);
  wpack_kernel<<<1024, 192, 0, stream>>>(Wih_f, Wih_b, wpk);
  pre_gemm_mfma<<<dim3(512, 8), 256, 0, stream>>>(feats, wpk, b_f, b_b, pre);
  lstm_valu_kernel<<<256, 512, 0, stream>>>(pre, Whh_f, Whh_b, hs);
  emis_kernel<<<4352, 256, 0, stream>>>(hs, h2tW, h2tb, em);
  score_kernel<<<128, 256, 0, stream>>>(tags, em, crf_s, crf_e, crf_t, score);
  crf_alpha_kernel<<<128, 64, 0, stream>>>(em, crf_s, crf_e, crf_t, logZ);
  final_kernel<<<1, 128, 0, stream>>>(logZ, score, out);
}